// Round 9
// baseline (7339.286 us; speedup 1.0000x reference)
//
#include <hip/hip_runtime.h>
#include <hip/hip_bf16.h>

typedef unsigned short ushort_t;
typedef unsigned long long u64_t;
typedef __attribute__((ext_vector_type(4))) float f32x4;
typedef __attribute__((ext_vector_type(8))) short short8;
typedef __attribute__((ext_vector_type(4))) unsigned int u32x4;
typedef __attribute__((ext_vector_type(4))) ushort_t u16x4;

#define BB 4
#define NN 2048
#define DD 512
#define H3 1536
#define SENT 0x7FC0ull  // bf16 qNaN: impossible h value since |h| < 1 strictly

__device__ __forceinline__ ushort_t f2bf(float f) {
    union { float f; unsigned u; } v; v.f = f;
    unsigned r = v.u + 0x7FFFu + ((v.u >> 16) & 1u);
    return (ushort_t)(r >> 16);
}
__device__ __forceinline__ float sigm(float x) { return 1.f / (1.f + __expf(-x)); }
__device__ __forceinline__ float tanhx(float x) { return 1.f - 2.f / (__expf(2.f * x) + 1.f); }
__device__ __forceinline__ f32x4 bf4_to_f32(u64_t v) {
    f32x4 r;
#pragma unroll
    for (int i = 0; i < 4; ++i) {
        union { unsigned u; float f; } c;
        c.u = (unsigned)((v >> (16 * i)) & 0xFFFFull) << 16;
        r[i] = c.f;
    }
    return r;
}

// ---------------- generic cvt fp32 -> bf16 ----------------
__global__ __launch_bounds__(256) void k_cvt(const float* __restrict__ src, ushort_t* __restrict__ dst, int n4) {
    int i = blockIdx.x * 256 + threadIdx.x;
    if (i < n4) {
        f32x4 f = *(const f32x4*)(src + 4 * (size_t)i);
        u16x4 u;
#pragma unroll
        for (int r = 0; r < 4; ++r) u[r] = f2bf(f[r]);
        *(u16x4*)(dst + 4 * (size_t)i) = u;
    }
}

// ---------------- sentinel fill (16B per thread) ----------------
__global__ __launch_bounds__(256) void k_fill(u32x4* __restrict__ dst, int n16) {
    int i = blockIdx.x * 256 + threadIdx.x;
    if (i < n16) dst[i] = (u32x4){0x7FC07FC0u, 0x7FC07FC0u, 0x7FC07FC0u, 0x7FC07FC0u};
}

// ---------------- W2s reduction: rows 8192..16383 of dec_W2 summed over d ----------------
__global__ __launch_bounds__(256) void k_w2s(const float* __restrict__ W2, const float* __restrict__ b2,
                                             ushort_t* __restrict__ W2s, float* __restrict__ b2s) {
    int gid = blockIdx.x * 256 + threadIdx.x; // 0..16383
    int r = gid >> 10, k = gid & 1023;
    float s = 0.f;
    for (int d = 0; d < 512; ++d) s += W2[(size_t)(8192 + d * 16 + r) * 1024 + k];
    W2s[r * 1024 + k] = f2bf(s);
    if (gid < 16) {
        float sb = 0.f;
        for (int d = 0; d < 512; ++d) sb += b2[8192 + d * 16 + gid];
        b2s[gid] = sb;
    }
}

// ---------------- generic bf16 GEMM: C[M,N] = A[M,K] @ W[N,K]^T (+bias)(+act) ----------------
// REMAP: A rows are t-major (m = t*4+b); write C row at b*2048+t instead.
template <int BIAS, int ACT, int OUTBF, int REMAP>
__global__ __launch_bounds__(256) void k_gemm(const ushort_t* __restrict__ A, const ushort_t* __restrict__ W,
                                              const float* __restrict__ bias, float* __restrict__ Cf,
                                              ushort_t* __restrict__ Cbf, int M, int N, int K) {
    __shared__ __align__(16) ushort_t As[128 * 72];
    __shared__ __align__(16) ushort_t Bs[128 * 72];
    const int tid = threadIdx.x;
    const int lane = tid & 63, wave = tid >> 6;
    const int col = lane & 15, g4 = lane >> 4;
    const int wm = wave >> 1, wn = wave & 1;
    const int m0 = blockIdx.y * 128, n0 = blockIdx.x * 128;

    f32x4 acc[4][4];
#pragma unroll
    for (int i = 0; i < 4; ++i)
#pragma unroll
        for (int j = 0; j < 4; ++j) acc[i][j] = (f32x4){0.f, 0.f, 0.f, 0.f};

    for (int k0 = 0; k0 < K; k0 += 64) {
#pragma unroll
        for (int c = 0; c < 4; ++c) {
            int cid = tid + 256 * c;
            int row = cid >> 3, c8 = cid & 7;
            u32x4 va = *(const u32x4*)(A + (size_t)(m0 + row) * K + k0 + c8 * 8);
            *(u32x4*)(&As[row * 72 + c8 * 8]) = va;
            u32x4 vb = (u32x4){0u, 0u, 0u, 0u};
            if (n0 + row < N) vb = *(const u32x4*)(W + (size_t)(n0 + row) * K + k0 + c8 * 8);
            *(u32x4*)(&Bs[row * 72 + c8 * 8]) = vb;
        }
        __syncthreads();
#pragma unroll
        for (int ks = 0; ks < 2; ++ks) {
            short8 af[4], bf_[4];
#pragma unroll
            for (int i = 0; i < 4; ++i)
                af[i] = *(const short8*)(&As[(wm * 64 + i * 16 + col) * 72 + ks * 32 + g4 * 8]);
#pragma unroll
            for (int j = 0; j < 4; ++j)
                bf_[j] = *(const short8*)(&Bs[(wn * 64 + j * 16 + col) * 72 + ks * 32 + g4 * 8]);
#pragma unroll
            for (int i = 0; i < 4; ++i)
#pragma unroll
                for (int j = 0; j < 4; ++j)
                    acc[i][j] = __builtin_amdgcn_mfma_f32_16x16x32_bf16(af[i], bf_[j], acc[i][j], 0, 0, 0);
        }
        __syncthreads();
    }
#pragma unroll
    for (int j = 0; j < 4; ++j) {
        int n = n0 + wn * 64 + j * 16 + col;
        if (n >= N) continue;
        float bv = 0.f;
        if (BIAS) bv = bias[n];
#pragma unroll
        for (int i = 0; i < 4; ++i) {
#pragma unroll
            for (int r = 0; r < 4; ++r) {
                int m = m0 + wm * 64 + i * 16 + g4 * 4 + r;
                size_t mr = REMAP ? ((size_t)(m & 3) * 2048 + (m >> 2)) : (size_t)m;
                float v = acc[i][j][r] + bv;
                if (ACT == 1) v = sigm(v);
                else if (ACT == 2) v = v * sigm(v);
                if (OUTBF) Cbf[mr * N + n] = f2bf(v);
                else Cf[mr * N + n] = v;
            }
        }
    }
}

// ---------------- persistent dual-GRU: unit-major line exchange + LDS distribution ----------------
// 8 blocks x 512 threads. blocks 0..3: GRU ap, 4..7: GRU su. 8 units(waves)/block,
// unit u = wg*8 + wave owns 16 h-cols, 48 W_hh rows in VGPRs.
// hexch[t][u][64] (bf16, address-unique per t, sentinel-prefilled): each unit
// publishes ONE contiguous 128B line (16 lanes x 8B agent-relaxed stores).
// 384 poll lanes each fetch one 8B granule of the 24 foreign units' lines into a
// double-buffered LDS h-tile; own units self-publish to LDS. hseq (t-major) gets a
// plain store for downstream GEMMs (not polled). xp prefetch issued AFTER the
// barrier + vmcnt(0) drain at iteration end => poll wait covers only the poll load.
__global__ __launch_bounds__(512, 1) void k_gru(const float* __restrict__ Whh0, const float* __restrict__ Whh1,
                                                const float* __restrict__ bhh0, const float* __restrict__ bhh1,
                                                const ushort_t* __restrict__ xpb0, const ushort_t* __restrict__ xpb1,
                                                ushort_t* __restrict__ hseq0, ushort_t* __restrict__ hseq1,
                                                ushort_t* __restrict__ hx0, ushort_t* __restrict__ hx1) {
    __shared__ __align__(16) ushort_t HB[2][4 * 520];  // [parity][b*520 + col], 8.3KB
    const int gru = blockIdx.x >> 2;
    const int wg = blockIdx.x & 3;
    const float* Whh = gru ? Whh1 : Whh0;
    const float* bhh = gru ? bhh1 : bhh0;
    const ushort_t* xpb = gru ? xpb1 : xpb0;
    ushort_t* hseq = gru ? hseq1 : hseq0;
    ushort_t* hx = gru ? hx1 : hx0;

    const int tid = threadIdx.x;
    const int wave = tid >> 6, lane = tid & 63;
    const int col = lane & 15, g4 = lane >> 4;
    const int u = wg * 8 + wave;  // 0..31
    const int c0 = u * 16;

    // poll assignment: 24 foreign units x 16 8B-granules = 384 lanes
    const bool gvalid = (tid < 384);
    const int uo = tid >> 4;
    const int gu = (uo < wg * 8) ? uo : uo + 8;     // foreign unit global id
    const int gq4 = tid & 15;                       // granule within the 64-elem line
    const int g_lds = (gq4 >> 2) * 520 + gu * 16 + (gq4 & 3) * 4;

    // preload bf16 A-fragments of the 48 W_hh rows this unit owns (stay in VGPRs)
    short8 af[3][16];
#pragma unroll
    for (int m = 0; m < 3; ++m) {
        int grow = m * 512 + c0 + col;
        const float* wr = Whh + (size_t)grow * 512;
#pragma unroll
        for (int q = 0; q < 16; ++q) {
            int k = q * 32 + g4 * 8;
            f32x4 f0 = *(const f32x4*)(wr + k);
            f32x4 f1 = *(const f32x4*)(wr + k + 4);
            short8 v;
#pragma unroll
            for (int i = 0; i < 4; ++i) v[i] = (short)f2bf(f0[i]);
#pragma unroll
            for (int i = 0; i < 4; ++i) v[4 + i] = (short)f2bf(f1[i]);
            af[m][q] = v;
        }
    }

    const bool active = (col < 4);
    const int b = active ? col : 0;
    const int j0 = c0 + g4 * 4;
    f32x4 bhr = {0.f, 0.f, 0.f, 0.f}, bhz = bhr, bhn = bhr;
    if (active) {
        bhr = *(const f32x4*)(bhh + j0);
        bhz = *(const f32x4*)(bhh + 512 + j0);
        bhn = *(const f32x4*)(bhh + 1024 + j0);
    }
    float hold[4] = {0.f, 0.f, 0.f, 0.f};
    long long budget = 1LL << 21;  // bounded retries: deterministic termination safeguard

    // prologue: xp(0)
    u64_t xr8 = 0, xz8 = 0, xn8 = 0;
    if (active) {
        const ushort_t* xpt = xpb + ((size_t)b * NN) * 1536;
        xr8 = *(const u64_t*)(xpt + j0);
        xz8 = *(const u64_t*)(xpt + 512 + j0);
        xn8 = *(const u64_t*)(xpt + 1024 + j0);
    }
    asm volatile("s_waitcnt vmcnt(0)" ::: "memory");

    for (int t = 0; t < NN; ++t) {
        if (t > 0 && gvalid) {
            // poll my single foreign 8B granule of h(t-1); only poll loads in flight
            const u64_t* gp = (const u64_t*)hx + ((size_t)(t - 1) * 32 + gu) * 16 + gq4;
            u64_t v = __hip_atomic_load(gp, __ATOMIC_RELAXED, __HIP_MEMORY_SCOPE_AGENT);
            while ((v & 0xFFFFull) == SENT && --budget >= 0)
                v = __hip_atomic_load(gp, __ATOMIC_RELAXED, __HIP_MEMORY_SCOPE_AGENT);
            *(u64_t*)(&HB[(t - 1) & 1][g_lds]) = v;
        }
        __syncthreads();  // LDS h(t-1) tile complete (own units wrote at t-1 tail)

        // issue xp(t+1) now: overlaps MFMA/gates, NOT the next poll
        u64_t xrn = 0, xzn = 0, xnn = 0;
        if (active && t + 1 < NN) {
            const ushort_t* xpt = xpb + ((size_t)b * NN + t + 1) * 1536;
            xrn = *(const u64_t*)(xpt + j0);
            xzn = *(const u64_t*)(xpt + 512 + j0);
            xnn = *(const u64_t*)(xpt + 1024 + j0);
        }
        f32x4 a0 = {0.f, 0.f, 0.f, 0.f}, a1 = a0, a2 = a0;
        if (t > 0) {
            const ushort_t* hb = &HB[(t - 1) & 1][(col & 3) * 520];
            short8 bf_[16];
#pragma unroll
            for (int q = 0; q < 16; ++q) bf_[q] = *(const short8*)(hb + q * 32 + g4 * 8);
#pragma unroll
            for (int q = 0; q < 16; ++q) {
                a0 = __builtin_amdgcn_mfma_f32_16x16x32_bf16(af[0][q], bf_[q], a0, 0, 0, 0);
                a1 = __builtin_amdgcn_mfma_f32_16x16x32_bf16(af[1][q], bf_[q], a1, 0, 0, 0);
                a2 = __builtin_amdgcn_mfma_f32_16x16x32_bf16(af[2][q], bf_[q], a2, 0, 0, 0);
            }
        }
        if (active) {
            f32x4 xr = bf4_to_f32(xr8), xz = bf4_to_f32(xz8), xn = bf4_to_f32(xn8);
            u16x4 pk;
#pragma unroll
            for (int r = 0; r < 4; ++r) {
                float rr = sigm(xr[r] + bhr[r] + a0[r]);
                float zz = sigm(xz[r] + bhz[r] + a1[r]);
                float nnv = tanhx(xn[r] + rr * (a2[r] + bhn[r]));
                float hv = (1.f - zz) * nnv + zz * hold[r];
                hold[r] = hv;
                pk[r] = f2bf(hv);
            }
            union { u16x4 p; u64_t u; } pc;
            pc.p = pk;
            // publish: one contiguous 128B line per unit (16 lanes x 8B)
            __hip_atomic_store((u64_t*)hx + ((size_t)t * 32 + u) * 16 + b * 4 + g4, pc.u, __ATOMIC_RELAXED,
                               __HIP_MEMORY_SCOPE_AGENT);
            // t-major hseq for downstream GEMMs (plain store, consumed after kernel end)
            *(u16x4*)(hseq + ((size_t)t * 4 + b) * 512 + j0) = pk;
            // self-publish to own block's LDS tile for step t+1
            *(u64_t*)(&HB[t & 1][b * 520 + j0]) = pc.u;
        }
        // drain all VMEM (xp prefetch + stores) so next poll waits only on itself
        asm volatile("s_waitcnt vmcnt(0)" ::: "memory");
        xr8 = xrn; xz8 = xzn; xn8 = xnn;
    }
}

// ---------------- sampled_action ----------------
__global__ __launch_bounds__(256) void k_sample(const float* __restrict__ ad, const float* __restrict__ eps,
                                                float* __restrict__ out2, int n) {
    int i = blockIdx.x * 256 + threadIdx.x;
    if (i < n) {
        float mean = ad[2 * (size_t)i];
        float lv = ad[2 * (size_t)i + 1];
        out2[i] = mean + __expf(0.5f * lv) * eps[i];
    }
}

// ---------------- assoc scan (3 phase), channels (b,d), length N ----------------
// beta_tm is t-major [(t*4+b)*512+d]; intent/gated are b-major [(b*NN+t)*512+d].
#define NC 32
#define LCH 64
__global__ __launch_bounds__(512) void k_scan1(const float* __restrict__ beta_tm, const float* __restrict__ intent,
                                               float* __restrict__ Asum, float* __restrict__ Bsum) {
    int d = threadIdx.x;
    int b = blockIdx.x / NC, c = blockIdx.x % NC;
    float A = 1.f, Bc = 0.f;
    for (int i = 0; i < LCH; ++i) {
        size_t t = (size_t)c * LCH + i;
        float a = beta_tm[(t * 4 + b) * 512 + d];
        float x = intent[((size_t)b * NN + t) * 512 + d] * (1.f - a);
        A *= a;
        Bc = a * Bc + x;
    }
    Asum[(b * NC + c) * 512 + d] = A;
    Bsum[(b * NC + c) * 512 + d] = Bc;
}
__global__ __launch_bounds__(512) void k_scan2(const float* __restrict__ Asum, const float* __restrict__ Bsum,
                                               float* __restrict__ P) {
    int d = threadIdx.x;
    int b = blockIdx.x;
    float carry = 0.f;
    for (int c = 0; c < NC; ++c) {
        int o = (b * NC + c) * 512 + d;
        P[o] = carry;
        carry = Asum[o] * carry + Bsum[o];
    }
}
__global__ __launch_bounds__(512) void k_scan3(const float* __restrict__ beta_tm, const float* __restrict__ intent,
                                               const float* __restrict__ P, float* __restrict__ gated,
                                               ushort_t* __restrict__ gated_bf) {
    int d = threadIdx.x;
    int b = blockIdx.x / NC, c = blockIdx.x % NC;
    float h = P[(b * NC + c) * 512 + d];
    for (int i = 0; i < LCH; ++i) {
        size_t t = (size_t)c * LCH + i;
        size_t idx = ((size_t)b * NN + t) * 512 + d;
        float a = beta_tm[(t * 4 + b) * 512 + d];
        float x = intent[idx] * (1.f - a);
        h = a * h + x;
        gated[idx] = h;
        gated_bf[idx] = f2bf(h);
    }
}

// ---------------- final contraction: t = sum_r w1*s ; out0 = resid + gated*t ----------------
__global__ __launch_bounds__(256) void k_contract(const float* __restrict__ w1s, const float* __restrict__ s,
                                                  const float* __restrict__ gated, const float* __restrict__ resid,
                                                  float* __restrict__ out0, int blk) {
    int gid = blockIdx.x * 256 + threadIdx.x; // 0 .. 1024*512-1
    int ml = gid >> 9, d = gid & 511;
    size_t m = (size_t)blk * 1024 + ml;
    const f32x4* wp = (const f32x4*)(w1s + ((size_t)ml * 8192 + d * 16));
    const f32x4* sp = (const f32x4*)(s + m * 16);
    float t = 0.f;
#pragma unroll
    for (int q = 0; q < 4; ++q) {
        f32x4 w = wp[q], sv = sp[q];
        t += w[0] * sv[0] + w[1] * sv[1] + w[2] * sv[2] + w[3] * sv[3];
    }
    size_t o = m * 512 + d;
    out0[o] = resid[o] + gated[o] * t;
}

extern "C" void kernel_launch(void* const* d_in, const int* in_sizes, int n_in, void* d_out, int out_size, void* d_ws,
                              size_t ws_size, hipStream_t stream) {
    const float* x = (const float*)d_in[0];
    const float* eps = (const float*)d_in[1];
    const float* ap_W_ih = (const float*)d_in[2];
    const float* ap_W_hh = (const float*)d_in[3];
    const float* ap_b_ih = (const float*)d_in[4];
    const float* ap_b_hh = (const float*)d_in[5];
    const float* su_W_ih = (const float*)d_in[6];
    const float* su_W_hh = (const float*)d_in[7];
    const float* su_b_ih = (const float*)d_in[8];
    const float* su_b_hh = (const float*)d_in[9];
    const float* readout_W = (const float*)d_in[10];
    const float* readout_b = (const float*)d_in[11];
    const float* beta_W = (const float*)d_in[12];
    const float* dec_W1 = (const float*)d_in[13];
    const float* dec_b1 = (const float*)d_in[14];
    const float* dec_W2 = (const float*)d_in[15];
    const float* dec_b2 = (const float*)d_in[16];

    float* out = (float*)d_out;
    float* out_ad = out + (size_t)4194304;   // action_dist (B,N,D,2)
    float* out_sa = out + (size_t)12582912;  // sampled_action

    char* ws = (char*)d_ws;
    size_t off = 0;
    auto alloc = [&](size_t bytes) -> void* {
        off = (off + 255) & ~(size_t)255;
        void* p = ws + off;
        off += bytes;
        return p;
    };
    ushort_t* x_bf = (ushort_t*)alloc((size_t)8192 * 512 * 2);
    ushort_t* wih_ap = (ushort_t*)alloc((size_t)1536 * 512 * 2);
    ushort_t* wih_su = (ushort_t*)alloc((size_t)1536 * 512 * 2);
    ushort_t* wro = (ushort_t*)alloc((size_t)1024 * 512 * 2);
    ushort_t* wbeta = (ushort_t*)alloc((size_t)512 * 512 * 2);
    ushort_t* wd1 = (ushort_t*)alloc((size_t)1024 * 512 * 2);
    ushort_t* wd2 = (ushort_t*)alloc((size_t)8192 * 1024 * 2);
    ushort_t* w2s = (ushort_t*)alloc((size_t)16 * 1024 * 2);
    float* b2s = (float*)alloc(64);
    ushort_t* hseq_ap = (ushort_t*)alloc((size_t)8192 * 512 * 2);  // t-major
    ushort_t* hseq_su = (ushort_t*)alloc((size_t)8192 * 512 * 2);  // t-major
    ushort_t* hx_ap = (ushort_t*)alloc((size_t)NN * 32 * 64 * 2);  // unit-major exchange ring
    ushort_t* hx_su = (ushort_t*)alloc((size_t)NN * 32 * 64 * 2);
    float* s_buf = (float*)alloc((size_t)8192 * 16 * 4);
    char* regionA = (char*)alloc(50331648);
    char* regionB = (char*)alloc(50331648);

    ushort_t* xpb_ap = (ushort_t*)regionA;   // bf16 xp, 25.2MB
    ushort_t* xpb_su = (ushort_t*)regionB;
    // region A reuse after GRU:
    float* beta_tm = (float*)regionA;
    float* gated = (float*)(regionA + 16777216);
    ushort_t* gated_bf = (ushort_t*)(regionA + 2 * 16777216);
    float* Asum = (float*)(regionA + 41943040);
    float* Bsum = (float*)(regionA + 41943040 + 262144);
    float* Pbuf = (float*)(regionA + 41943040 + 524288);
    // region B reuse after GRU:
    ushort_t* hdec_bf = (ushort_t*)regionB;
    float* w1s = (float*)(regionB + 16777216);

    // zero KL output
    hipMemsetAsync(out + (size_t)(out_size - 1), 0, 4, stream);

    // sentinel-fill the exchange rings (re-done every launch; replay-safe)
    k_fill<<<2048, 256, 0, stream>>>((u32x4*)hx_ap, 524288);
    k_fill<<<2048, 256, 0, stream>>>((u32x4*)hx_su, 524288);

    // weight / input conversions to bf16
    k_cvt<<<768, 256, 0, stream>>>(ap_W_ih, wih_ap, 196608);
    k_cvt<<<768, 256, 0, stream>>>(su_W_ih, wih_su, 196608);
    k_cvt<<<512, 256, 0, stream>>>(readout_W, wro, 131072);
    k_cvt<<<256, 256, 0, stream>>>(beta_W, wbeta, 65536);
    k_cvt<<<512, 256, 0, stream>>>(dec_W1, wd1, 131072);
    k_cvt<<<8192, 256, 0, stream>>>(dec_W2, wd2, 2097152);
    k_cvt<<<4096, 256, 0, stream>>>(x, x_bf, 1048576);
    k_w2s<<<64, 256, 0, stream>>>(dec_W2, dec_b2, w2s, b2s);

    // xp projections (bf16 out)
    k_gemm<1, 0, 1, 0><<<dim3(12, 64), 256, 0, stream>>>(x_bf, wih_ap, ap_b_ih, nullptr, xpb_ap, 8192, 1536, 512);
    k_gemm<1, 0, 1, 0><<<dim3(12, 64), 256, 0, stream>>>(x_bf, wih_su, su_b_ih, nullptr, xpb_su, 8192, 1536, 512);

    // both GRUs: 8 persistent blocks (4 per GRU), unit-major line exchange
    k_gru<<<8, 512, 0, stream>>>(ap_W_hh, su_W_hh, ap_b_hh, su_b_hh, xpb_ap, xpb_su, hseq_ap, hseq_su, hx_ap, hx_su);

    // readout -> action_dist (REMAP t-major rows -> b-major out), then sampled_action
    k_gemm<1, 0, 0, 1><<<dim3(8, 64), 256, 0, stream>>>(hseq_ap, wro, readout_b, out_ad, nullptr, 8192, 1024, 512);
    k_sample<<<16384, 256, 0, stream>>>(out_ad, eps, out_sa, 4194304);

    // switch_beta (t-major output; scan consumes t-major)
    k_gemm<0, 1, 0, 0><<<dim3(4, 64), 256, 0, stream>>>(hseq_su, wbeta, nullptr, beta_tm, nullptr, 8192, 512, 512);

    // associative scan -> gated
    k_scan1<<<4 * NC, 512, 0, stream>>>(beta_tm, out_sa, Asum, Bsum);
    k_scan2<<<4, 512, 0, stream>>>(Asum, Bsum, Pbuf);
    k_scan3<<<4 * NC, 512, 0, stream>>>(beta_tm, out_sa, Pbuf, gated, gated_bf);

    // decoder layer 1 (SiLU, bf16 out)
    k_gemm<1, 2, 1, 0><<<dim3(8, 64), 256, 0, stream>>>(gated_bf, wd1, dec_b1, nullptr, hdec_bf, 8192, 1024, 512);

    // s = hdec @ W2s^T + b2s
    k_gemm<1, 0, 0, 0><<<dim3(1, 64), 256, 0, stream>>>(hdec_bf, w2s, b2s, s_buf, nullptr, 8192, 16, 1024);

    // blocked w1 GEMM + contraction + final output
    for (int blk = 0; blk < 8; ++blk) {
        k_gemm<1, 0, 0, 0><<<dim3(64, 8), 256, 0, stream>>>(hdec_bf + (size_t)blk * 1024 * 1024, wd2, dec_b2, w1s,
                                                            nullptr, 1024, 8192, 1024);
        k_contract<<<2048, 256, 0, stream>>>(w1s, s_buf, gated, x, out, blk);
    }
}

// Round 11
// 7203.905 us; speedup vs baseline: 1.0188x; 1.0188x over previous
//
#include <hip/hip_runtime.h>
#include <hip/hip_bf16.h>

typedef unsigned short ushort_t;
typedef unsigned long long u64_t;
typedef __attribute__((ext_vector_type(4))) float f32x4;
typedef __attribute__((ext_vector_type(8))) short short8;
typedef __attribute__((ext_vector_type(4))) unsigned int u32x4;
typedef __attribute__((ext_vector_type(4))) ushort_t u16x4;

#define BB 4
#define NN 2048
#define DD 512
#define H3 1536
#define SENT 0x7FC0ull  // bf16 qNaN: impossible h value since |h| < 1 strictly

__device__ __forceinline__ ushort_t f2bf(float f) {
    union { float f; unsigned u; } v; v.f = f;
    unsigned r = v.u + 0x7FFFu + ((v.u >> 16) & 1u);
    return (ushort_t)(r >> 16);
}
__device__ __forceinline__ float sigm(float x) { return 1.f / (1.f + __expf(-x)); }
__device__ __forceinline__ float tanhx(float x) { return 1.f - 2.f / (__expf(2.f * x) + 1.f); }
__device__ __forceinline__ f32x4 bf4_to_f32(u64_t v) {
    f32x4 r;
#pragma unroll
    for (int i = 0; i < 4; ++i) {
        union { unsigned u; float f; } c;
        c.u = (unsigned)((v >> (16 * i)) & 0xFFFFull) << 16;
        r[i] = c.f;
    }
    return r;
}

// ---------------- generic cvt fp32 -> bf16 ----------------
__global__ __launch_bounds__(256) void k_cvt(const float* __restrict__ src, ushort_t* __restrict__ dst, int n4) {
    int i = blockIdx.x * 256 + threadIdx.x;
    if (i < n4) {
        f32x4 f = *(const f32x4*)(src + 4 * (size_t)i);
        u16x4 u;
#pragma unroll
        for (int r = 0; r < 4; ++r) u[r] = f2bf(f[r]);
        *(u16x4*)(dst + 4 * (size_t)i) = u;
    }
}

// ---------------- sentinel fill (16B per thread) ----------------
__global__ __launch_bounds__(256) void k_fill(u32x4* __restrict__ dst, int n16) {
    int i = blockIdx.x * 256 + threadIdx.x;
    if (i < n16) dst[i] = (u32x4){0x7FC07FC0u, 0x7FC07FC0u, 0x7FC07FC0u, 0x7FC07FC0u};
}

// ---------------- remap hx (unit-major exchange ring) -> hseq (t-major) ----------------
// hx u64 index i = t*512 + u*16 + b*4 + g4
// hseq bf16 row (t*4+b) has 512 cols = 128 u64; col u64 = u*4 + g4
__global__ __launch_bounds__(256) void k_remap(const u64_t* __restrict__ hx, u64_t* __restrict__ hseq) {
    int i = blockIdx.x * 256 + threadIdx.x;
    if (i < NN * 512) {
        int t = i >> 9, r = i & 511;
        int u = r >> 4, b = (r >> 2) & 3, g4 = r & 3;
        hseq[((size_t)(t * 4 + b)) * 128 + u * 4 + g4] = hx[i];
    }
}

// ---------------- W2s reduction: rows 8192..16383 of dec_W2 summed over d ----------------
__global__ __launch_bounds__(256) void k_w2s(const float* __restrict__ W2, const float* __restrict__ b2,
                                             ushort_t* __restrict__ W2s, float* __restrict__ b2s) {
    int gid = blockIdx.x * 256 + threadIdx.x; // 0..16383
    int r = gid >> 10, k = gid & 1023;
    float s = 0.f;
    for (int d = 0; d < 512; ++d) s += W2[(size_t)(8192 + d * 16 + r) * 1024 + k];
    W2s[r * 1024 + k] = f2bf(s);
    if (gid < 16) {
        float sb = 0.f;
        for (int d = 0; d < 512; ++d) sb += b2[8192 + d * 16 + gid];
        b2s[gid] = sb;
    }
}

// ---------------- generic bf16 GEMM: C[M,N] = A[M,K] @ W[N,K]^T (+bias)(+act) ----------------
// REMAP: A rows are t-major (m = t*4+b); write C row at b*2048+t instead.
template <int BIAS, int ACT, int OUTBF, int REMAP>
__global__ __launch_bounds__(256) void k_gemm(const ushort_t* __restrict__ A, const ushort_t* __restrict__ W,
                                              const float* __restrict__ bias, float* __restrict__ Cf,
                                              ushort_t* __restrict__ Cbf, int M, int N, int K) {
    __shared__ __align__(16) ushort_t As[128 * 72];
    __shared__ __align__(16) ushort_t Bs[128 * 72];
    const int tid = threadIdx.x;
    const int lane = tid & 63, wave = tid >> 6;
    const int col = lane & 15, g4 = lane >> 4;
    const int wm = wave >> 1, wn = wave & 1;
    const int m0 = blockIdx.y * 128, n0 = blockIdx.x * 128;

    f32x4 acc[4][4];
#pragma unroll
    for (int i = 0; i < 4; ++i)
#pragma unroll
        for (int j = 0; j < 4; ++j) acc[i][j] = (f32x4){0.f, 0.f, 0.f, 0.f};

    for (int k0 = 0; k0 < K; k0 += 64) {
#pragma unroll
        for (int c = 0; c < 4; ++c) {
            int cid = tid + 256 * c;
            int row = cid >> 3, c8 = cid & 7;
            u32x4 va = *(const u32x4*)(A + (size_t)(m0 + row) * K + k0 + c8 * 8);
            *(u32x4*)(&As[row * 72 + c8 * 8]) = va;
            u32x4 vb = (u32x4){0u, 0u, 0u, 0u};
            if (n0 + row < N) vb = *(const u32x4*)(W + (size_t)(n0 + row) * K + k0 + c8 * 8);
            *(u32x4*)(&Bs[row * 72 + c8 * 8]) = vb;
        }
        __syncthreads();
#pragma unroll
        for (int ks = 0; ks < 2; ++ks) {
            short8 af[4], bf_[4];
#pragma unroll
            for (int i = 0; i < 4; ++i)
                af[i] = *(const short8*)(&As[(wm * 64 + i * 16 + col) * 72 + ks * 32 + g4 * 8]);
#pragma unroll
            for (int j = 0; j < 4; ++j)
                bf_[j] = *(const short8*)(&Bs[(wn * 64 + j * 16 + col) * 72 + ks * 32 + g4 * 8]);
#pragma unroll
            for (int i = 0; i < 4; ++i)
#pragma unroll
                for (int j = 0; j < 4; ++j)
                    acc[i][j] = __builtin_amdgcn_mfma_f32_16x16x32_bf16(af[i], bf_[j], acc[i][j], 0, 0, 0);
        }
        __syncthreads();
    }
#pragma unroll
    for (int j = 0; j < 4; ++j) {
        int n = n0 + wn * 64 + j * 16 + col;
        if (n >= N) continue;
        float bv = 0.f;
        if (BIAS) bv = bias[n];
#pragma unroll
        for (int i = 0; i < 4; ++i) {
#pragma unroll
            for (int r = 0; r < 4; ++r) {
                int m = m0 + wm * 64 + i * 16 + g4 * 4 + r;
                size_t mr = REMAP ? ((size_t)(m & 3) * 2048 + (m >> 2)) : (size_t)m;
                float v = acc[i][j][r] + bv;
                if (ACT == 1) v = sigm(v);
                else if (ACT == 2) v = v * sigm(v);
                if (OUTBF) Cbf[mr * N + n] = f2bf(v);
                else Cf[mr * N + n] = v;
            }
        }
    }
}

// ---------------- persistent dual-GRU: line exchange, fire-and-forget stores ----------------
// 8 blocks x 512 threads. blocks 0..3: GRU ap, 4..7: GRU su. 8 units(waves)/block,
// unit u = wg*8 + wave owns 16 h-cols, 48 W_hh rows in VGPRs.
// hx[t][u][64] (bf16, address-unique per t, sentinel-prefilled): each unit publishes
// ONE contiguous 128B line (16 lanes x 8B agent-relaxed stores, fire-and-forget).
// 384 poll lanes each fetch one foreign 8B granule into a double-buffered LDS tile;
// own units self-publish to LDS. ONE barrier/step. xp prefetch issued BEFORE the
// poll (its HBM latency and our store acks overlap the mandatory foreign-publish
// wait). NO explicit drains (r9 lesson: every non-poll wait is pure loss).
__global__ __launch_bounds__(512, 1) void k_gru(const float* __restrict__ Whh0, const float* __restrict__ Whh1,
                                                const float* __restrict__ bhh0, const float* __restrict__ bhh1,
                                                const ushort_t* __restrict__ xpb0, const ushort_t* __restrict__ xpb1,
                                                ushort_t* __restrict__ hx0, ushort_t* __restrict__ hx1) {
    __shared__ __align__(16) ushort_t HB[2][4 * 520];  // [parity][b*520 + col], 8.3KB
    const int gru = blockIdx.x >> 2;
    const int wg = blockIdx.x & 3;
    const float* Whh = gru ? Whh1 : Whh0;
    const float* bhh = gru ? bhh1 : bhh0;
    const ushort_t* xpb = gru ? xpb1 : xpb0;
    ushort_t* hx = gru ? hx1 : hx0;

    const int tid = threadIdx.x;
    const int wave = tid >> 6, lane = tid & 63;
    const int col = lane & 15, g4 = lane >> 4;
    const int u = wg * 8 + wave;  // 0..31
    const int c0 = u * 16;

    // poll assignment: 24 foreign units x 16 8B-granules = 384 lanes
    const bool gvalid = (tid < 384);
    const int uo = tid >> 4;
    const int gu = (uo < wg * 8) ? uo : uo + 8;     // foreign unit global id
    const int gq4 = tid & 15;                       // granule within the 64-elem line
    const int g_lds = (gq4 >> 2) * 520 + gu * 16 + (gq4 & 3) * 4;

    // preload bf16 A-fragments of the 48 W_hh rows this unit owns (stay in regs)
    short8 af[3][16];
#pragma unroll
    for (int m = 0; m < 3; ++m) {
        int grow = m * 512 + c0 + col;
        const float* wr = Whh + (size_t)grow * 512;
#pragma unroll
        for (int q = 0; q < 16; ++q) {
            int k = q * 32 + g4 * 8;
            f32x4 f0 = *(const f32x4*)(wr + k);
            f32x4 f1 = *(const f32x4*)(wr + k + 4);
            short8 v;
#pragma unroll
            for (int i = 0; i < 4; ++i) v[i] = (short)f2bf(f0[i]);
#pragma unroll
            for (int i = 0; i < 4; ++i) v[4 + i] = (short)f2bf(f1[i]);
            af[m][q] = v;
        }
    }

    const bool active = (col < 4);
    const int b = active ? col : 0;
    const int j0 = c0 + g4 * 4;
    f32x4 bhr = {0.f, 0.f, 0.f, 0.f}, bhz = bhr, bhn = bhr;
    if (active) {
        bhr = *(const f32x4*)(bhh + j0);
        bhz = *(const f32x4*)(bhh + 512 + j0);
        bhn = *(const f32x4*)(bhh + 1024 + j0);
    }
    float hold[4] = {0.f, 0.f, 0.f, 0.f};
    long long budget = 1LL << 21;  // bounded retries: deterministic termination safeguard

    // prologue: xp(0)
    u64_t xr8 = 0, xz8 = 0, xn8 = 0;
    if (active) {
        const ushort_t* xpt = xpb + ((size_t)b * NN) * 1536;
        xr8 = *(const u64_t*)(xpt + j0);
        xz8 = *(const u64_t*)(xpt + 512 + j0);
        xn8 = *(const u64_t*)(xpt + 1024 + j0);
    }

    for (int t = 0; t < NN; ++t) {
        // issue xp(t+1) BEFORE the poll: HBM latency overlaps the foreign-publish wait
        u64_t xrn = 0, xzn = 0, xnn = 0;
        if (active && t + 1 < NN) {
            const ushort_t* xpt = xpb + ((size_t)b * NN + t + 1) * 1536;
            xrn = *(const u64_t*)(xpt + j0);
            xzn = *(const u64_t*)(xpt + 512 + j0);
            xnn = *(const u64_t*)(xpt + 1024 + j0);
        }
        if (t > 0 && gvalid) {
            // poll my single foreign 8B granule of h(t-1)
            const u64_t* gp = (const u64_t*)hx + ((size_t)(t - 1) * 32 + gu) * 16 + gq4;
            u64_t v = __hip_atomic_load(gp, __ATOMIC_RELAXED, __HIP_MEMORY_SCOPE_AGENT);
            while ((v & 0xFFFFull) == SENT && --budget >= 0)
                v = __hip_atomic_load(gp, __ATOMIC_RELAXED, __HIP_MEMORY_SCOPE_AGENT);
            *(u64_t*)(&HB[(t - 1) & 1][g_lds]) = v;
        }
        __syncthreads();  // LDS h(t-1) tile complete (own units wrote at t-1 tail)
        f32x4 a0 = {0.f, 0.f, 0.f, 0.f}, a1 = a0, a2 = a0;
        if (t > 0) {
            const ushort_t* hb = &HB[(t - 1) & 1][(col & 3) * 520];
            short8 bf_[16];
#pragma unroll
            for (int q = 0; q < 16; ++q) bf_[q] = *(const short8*)(hb + q * 32 + g4 * 8);
#pragma unroll
            for (int q = 0; q < 16; ++q) {
                a0 = __builtin_amdgcn_mfma_f32_16x16x32_bf16(af[0][q], bf_[q], a0, 0, 0, 0);
                a1 = __builtin_amdgcn_mfma_f32_16x16x32_bf16(af[1][q], bf_[q], a1, 0, 0, 0);
                a2 = __builtin_amdgcn_mfma_f32_16x16x32_bf16(af[2][q], bf_[q], a2, 0, 0, 0);
            }
        }
        if (active) {
            f32x4 xr = bf4_to_f32(xr8), xz = bf4_to_f32(xz8), xn = bf4_to_f32(xn8);
            u16x4 pk;
#pragma unroll
            for (int r = 0; r < 4; ++r) {
                float rr = sigm(xr[r] + bhr[r] + a0[r]);
                float zz = sigm(xz[r] + bhz[r] + a1[r]);
                float nnv = tanhx(xn[r] + rr * (a2[r] + bhn[r]));
                float hv = (1.f - zz) * nnv + zz * hold[r];
                hold[r] = hv;
                pk[r] = f2bf(hv);
            }
            union { u16x4 p; u64_t u; } pc;
            pc.p = pk;
            // publish: one contiguous 128B line per unit, fire-and-forget
            __hip_atomic_store((u64_t*)hx + ((size_t)t * 32 + u) * 16 + b * 4 + g4, pc.u, __ATOMIC_RELAXED,
                               __HIP_MEMORY_SCOPE_AGENT);
            // self-publish to own block's LDS tile for step t+1
            *(u64_t*)(&HB[t & 1][b * 520 + j0]) = pc.u;
        }
        xr8 = xrn; xz8 = xzn; xn8 = xnn;
    }
}

// ---------------- sampled_action ----------------
__global__ __launch_bounds__(256) void k_sample(const float* __restrict__ ad, const float* __restrict__ eps,
                                                float* __restrict__ out2, int n) {
    int i = blockIdx.x * 256 + threadIdx.x;
    if (i < n) {
        float mean = ad[2 * (size_t)i];
        float lv = ad[2 * (size_t)i + 1];
        out2[i] = mean + __expf(0.5f * lv) * eps[i];
    }
}

// ---------------- assoc scan (3 phase), channels (b,d), length N ----------------
// beta_tm is t-major [(t*4+b)*512+d]; intent/gated are b-major [(b*NN+t)*512+d].
#define NC 32
#define LCH 64
__global__ __launch_bounds__(512) void k_scan1(const float* __restrict__ beta_tm, const float* __restrict__ intent,
                                               float* __restrict__ Asum, float* __restrict__ Bsum) {
    int d = threadIdx.x;
    int b = blockIdx.x / NC, c = blockIdx.x % NC;
    float A = 1.f, Bc = 0.f;
    for (int i = 0; i < LCH; ++i) {
        size_t t = (size_t)c * LCH + i;
        float a = beta_tm[(t * 4 + b) * 512 + d];
        float x = intent[((size_t)b * NN + t) * 512 + d] * (1.f - a);
        A *= a;
        Bc = a * Bc + x;
    }
    Asum[(b * NC + c) * 512 + d] = A;
    Bsum[(b * NC + c) * 512 + d] = Bc;
}
__global__ __launch_bounds__(512) void k_scan2(const float* __restrict__ Asum, const float* __restrict__ Bsum,
                                               float* __restrict__ P) {
    int d = threadIdx.x;
    int b = blockIdx.x;
    float carry = 0.f;
    for (int c = 0; c < NC; ++c) {
        int o = (b * NC + c) * 512 + d;
        P[o] = carry;
        carry = Asum[o] * carry + Bsum[o];
    }
}
__global__ __launch_bounds__(512) void k_scan3(const float* __restrict__ beta_tm, const float* __restrict__ intent,
                                               const float* __restrict__ P, float* __restrict__ gated,
                                               ushort_t* __restrict__ gated_bf) {
    int d = threadIdx.x;
    int b = blockIdx.x / NC, c = blockIdx.x % NC;
    float h = P[(b * NC + c) * 512 + d];
    for (int i = 0; i < LCH; ++i) {
        size_t t = (size_t)c * LCH + i;
        size_t idx = ((size_t)b * NN + t) * 512 + d;
        float a = beta_tm[(t * 4 + b) * 512 + d];
        float x = intent[idx] * (1.f - a);
        h = a * h + x;
        gated[idx] = h;
        gated_bf[idx] = f2bf(h);
    }
}

// ---------------- final contraction: t = sum_r w1*s ; out0 = resid + gated*t ----------------
__global__ __launch_bounds__(256) void k_contract(const float* __restrict__ w1s, const float* __restrict__ s,
                                                  const float* __restrict__ gated, const float* __restrict__ resid,
                                                  float* __restrict__ out0, int blk) {
    int gid = blockIdx.x * 256 + threadIdx.x; // 0 .. 1024*512-1
    int ml = gid >> 9, d = gid & 511;
    size_t m = (size_t)blk * 1024 + ml;
    const f32x4* wp = (const f32x4*)(w1s + ((size_t)ml * 8192 + d * 16));
    const f32x4* sp = (const f32x4*)(s + m * 16);
    float t = 0.f;
#pragma unroll
    for (int q = 0; q < 4; ++q) {
        f32x4 w = wp[q], sv = sp[q];
        t += w[0] * sv[0] + w[1] * sv[1] + w[2] * sv[2] + w[3] * sv[3];
    }
    size_t o = m * 512 + d;
    out0[o] = resid[o] + gated[o] * t;
}

extern "C" void kernel_launch(void* const* d_in, const int* in_sizes, int n_in, void* d_out, int out_size, void* d_ws,
                              size_t ws_size, hipStream_t stream) {
    const float* x = (const float*)d_in[0];
    const float* eps = (const float*)d_in[1];
    const float* ap_W_ih = (const float*)d_in[2];
    const float* ap_W_hh = (const float*)d_in[3];
    const float* ap_b_ih = (const float*)d_in[4];
    const float* ap_b_hh = (const float*)d_in[5];
    const float* su_W_ih = (const float*)d_in[6];
    const float* su_W_hh = (const float*)d_in[7];
    const float* su_b_ih = (const float*)d_in[8];
    const float* su_b_hh = (const float*)d_in[9];
    const float* readout_W = (const float*)d_in[10];
    const float* readout_b = (const float*)d_in[11];
    const float* beta_W = (const float*)d_in[12];
    const float* dec_W1 = (const float*)d_in[13];
    const float* dec_b1 = (const float*)d_in[14];
    const float* dec_W2 = (const float*)d_in[15];
    const float* dec_b2 = (const float*)d_in[16];

    float* out = (float*)d_out;
    float* out_ad = out + (size_t)4194304;   // action_dist (B,N,D,2)
    float* out_sa = out + (size_t)12582912;  // sampled_action

    char* ws = (char*)d_ws;
    size_t off = 0;
    auto alloc = [&](size_t bytes) -> void* {
        off = (off + 255) & ~(size_t)255;
        void* p = ws + off;
        off += bytes;
        return p;
    };
    ushort_t* x_bf = (ushort_t*)alloc((size_t)8192 * 512 * 2);
    ushort_t* wih_ap = (ushort_t*)alloc((size_t)1536 * 512 * 2);
    ushort_t* wih_su = (ushort_t*)alloc((size_t)1536 * 512 * 2);
    ushort_t* wro = (ushort_t*)alloc((size_t)1024 * 512 * 2);
    ushort_t* wbeta = (ushort_t*)alloc((size_t)512 * 512 * 2);
    ushort_t* wd1 = (ushort_t*)alloc((size_t)1024 * 512 * 2);
    ushort_t* wd2 = (ushort_t*)alloc((size_t)8192 * 1024 * 2);
    ushort_t* w2s = (ushort_t*)alloc((size_t)16 * 1024 * 2);
    float* b2s = (float*)alloc(64);
    ushort_t* hseq_ap = (ushort_t*)alloc((size_t)8192 * 512 * 2);  // t-major (rebuilt by k_remap)
    ushort_t* hseq_su = (ushort_t*)alloc((size_t)8192 * 512 * 2);  // t-major
    ushort_t* hx_ap = (ushort_t*)alloc((size_t)NN * 32 * 64 * 2);  // unit-major exchange ring
    ushort_t* hx_su = (ushort_t*)alloc((size_t)NN * 32 * 64 * 2);
    float* s_buf = (float*)alloc((size_t)8192 * 16 * 4);
    char* regionA = (char*)alloc(50331648);
    char* regionB = (char*)alloc(50331648);

    ushort_t* xpb_ap = (ushort_t*)regionA;   // bf16 xp, 25.2MB
    ushort_t* xpb_su = (ushort_t*)regionB;
    // region A reuse after GRU:
    float* beta_tm = (float*)regionA;
    float* gated = (float*)(regionA + 16777216);
    ushort_t* gated_bf = (ushort_t*)(regionA + 2 * 16777216);
    float* Asum = (float*)(regionA + 41943040);
    float* Bsum = (float*)(regionA + 41943040 + 262144);
    float* Pbuf = (float*)(regionA + 41943040 + 524288);
    // region B reuse after GRU:
    ushort_t* hdec_bf = (ushort_t*)regionB;
    float* w1s = (float*)(regionB + 16777216);

    // zero KL output
    hipMemsetAsync(out + (size_t)(out_size - 1), 0, 4, stream);

    // sentinel-fill the exchange rings (re-done every launch; replay-safe)
    k_fill<<<2048, 256, 0, stream>>>((u32x4*)hx_ap, 524288);
    k_fill<<<2048, 256, 0, stream>>>((u32x4*)hx_su, 524288);

    // weight / input conversions to bf16
    k_cvt<<<768, 256, 0, stream>>>(ap_W_ih, wih_ap, 196608);
    k_cvt<<<768, 256, 0, stream>>>(su_W_ih, wih_su, 196608);
    k_cvt<<<512, 256, 0, stream>>>(readout_W, wro, 131072);
    k_cvt<<<256, 256, 0, stream>>>(beta_W, wbeta, 65536);
    k_cvt<<<512, 256, 0, stream>>>(dec_W1, wd1, 131072);
    k_cvt<<<8192, 256, 0, stream>>>(dec_W2, wd2, 2097152);
    k_cvt<<<4096, 256, 0, stream>>>(x, x_bf, 1048576);
    k_w2s<<<64, 256, 0, stream>>>(dec_W2, dec_b2, w2s, b2s);

    // xp projections (bf16 out)
    k_gemm<1, 0, 1, 0><<<dim3(12, 64), 256, 0, stream>>>(x_bf, wih_ap, ap_b_ih, nullptr, xpb_ap, 8192, 1536, 512);
    k_gemm<1, 0, 1, 0><<<dim3(12, 64), 256, 0, stream>>>(x_bf, wih_su, su_b_ih, nullptr, xpb_su, 8192, 1536, 512);

    // both GRUs: 8 persistent blocks (4 per GRU), line exchange, fire-and-forget stores
    k_gru<<<8, 512, 0, stream>>>(ap_W_hh, su_W_hh, ap_b_hh, su_b_hh, xpb_ap, xpb_su, hx_ap, hx_su);

    // rebuild t-major hseq from the exchange rings (removes per-step duplicate store)
    k_remap<<<4096, 256, 0, stream>>>((const u64_t*)hx_ap, (u64_t*)hseq_ap);
    k_remap<<<4096, 256, 0, stream>>>((const u64_t*)hx_su, (u64_t*)hseq_su);

    // readout -> action_dist (REMAP t-major rows -> b-major out), then sampled_action
    k_gemm<1, 0, 0, 1><<<dim3(8, 64), 256, 0, stream>>>(hseq_ap, wro, readout_b, out_ad, nullptr, 8192, 1024, 512);
    k_sample<<<16384, 256, 0, stream>>>(out_ad, eps, out_sa, 4194304);

    // switch_beta (t-major output; scan consumes t-major)
    k_gemm<0, 1, 0, 0><<<dim3(4, 64), 256, 0, stream>>>(hseq_su, wbeta, nullptr, beta_tm, nullptr, 8192, 512, 512);

    // associative scan -> gated
    k_scan1<<<4 * NC, 512, 0, stream>>>(beta_tm, out_sa, Asum, Bsum);
    k_scan2<<<4, 512, 0, stream>>>(Asum, Bsum, Pbuf);
    k_scan3<<<4 * NC, 512, 0, stream>>>(beta_tm, out_sa, Pbuf, gated, gated_bf);

    // decoder layer 1 (SiLU, bf16 out)
    k_gemm<1, 2, 1, 0><<<dim3(8, 64), 256, 0, stream>>>(gated_bf, wd1, dec_b1, nullptr, hdec_bf, 8192, 1024, 512);

    // s = hdec @ W2s^T + b2s
    k_gemm<1, 0, 0, 0><<<dim3(1, 64), 256, 0, stream>>>(hdec_bf, w2s, b2s, s_buf, nullptr, 8192, 16, 1024);

    // blocked w1 GEMM + contraction + final output
    for (int blk = 0; blk < 8; ++blk) {
        k_gemm<1, 0, 0, 0><<<dim3(64, 8), 256, 0, stream>>>(hdec_bf + (size_t)blk * 1024 * 1024, wd2, dec_b2, w1s,
                                                            nullptr, 1024, 8192, 1024);
        k_contract<<<2048, 256, 0, stream>>>(w1s, s_buf, gated, x, out, blk);
    }
}

// Round 13
// 6415.244 us; speedup vs baseline: 1.1440x; 1.1229x over previous
//
#include <hip/hip_runtime.h>
#include <hip/hip_bf16.h>

typedef unsigned short ushort_t;
typedef unsigned long long u64_t;
typedef __attribute__((ext_vector_type(4))) float f32x4;
typedef __attribute__((ext_vector_type(8))) short short8;
typedef __attribute__((ext_vector_type(4))) unsigned int u32x4;
typedef __attribute__((ext_vector_type(4))) ushort_t u16x4;

#define BB 4
#define NN 2048
#define DD 512
#define H3 1536
#define SENT 0x7FC0ull  // bf16 qNaN: impossible h value since |h| < 1 strictly

__device__ __forceinline__ ushort_t f2bf(float f) {
    union { float f; unsigned u; } v; v.f = f;
    unsigned r = v.u + 0x7FFFu + ((v.u >> 16) & 1u);
    return (ushort_t)(r >> 16);
}
__device__ __forceinline__ float sigm(float x) { return 1.f / (1.f + __expf(-x)); }
__device__ __forceinline__ float tanhx(float x) { return 1.f - 2.f / (__expf(2.f * x) + 1.f); }
__device__ __forceinline__ f32x4 bf4_to_f32(u64_t v) {
    f32x4 r;
#pragma unroll
    for (int i = 0; i < 4; ++i) {
        union { unsigned u; float f; } c;
        c.u = (unsigned)((v >> (16 * i)) & 0xFFFFull) << 16;
        r[i] = c.f;
    }
    return r;
}

// ---------------- generic cvt fp32 -> bf16 ----------------
__global__ __launch_bounds__(256) void k_cvt(const float* __restrict__ src, ushort_t* __restrict__ dst, int n4) {
    int i = blockIdx.x * 256 + threadIdx.x;
    if (i < n4) {
        f32x4 f = *(const f32x4*)(src + 4 * (size_t)i);
        u16x4 u;
#pragma unroll
        for (int r = 0; r < 4; ++r) u[r] = f2bf(f[r]);
        *(u16x4*)(dst + 4 * (size_t)i) = u;
    }
}

// ---------------- sentinel fill (16B per thread) ----------------
__global__ __launch_bounds__(256) void k_fill(u32x4* __restrict__ dst, int n16) {
    int i = blockIdx.x * 256 + threadIdx.x;
    if (i < n16) dst[i] = (u32x4){0x7FC07FC0u, 0x7FC07FC0u, 0x7FC07FC0u, 0x7FC07FC0u};
}

// ---------------- W2s reduction: rows 8192..16383 of dec_W2 summed over d ----------------
__global__ __launch_bounds__(256) void k_w2s(const float* __restrict__ W2, const float* __restrict__ b2,
                                             ushort_t* __restrict__ W2s, float* __restrict__ b2s) {
    int gid = blockIdx.x * 256 + threadIdx.x; // 0..16383
    int r = gid >> 10, k = gid & 1023;
    float s = 0.f;
    for (int d = 0; d < 512; ++d) s += W2[(size_t)(8192 + d * 16 + r) * 1024 + k];
    W2s[r * 1024 + k] = f2bf(s);
    if (gid < 16) {
        float sb = 0.f;
        for (int d = 0; d < 512; ++d) sb += b2[8192 + d * 16 + gid];
        b2s[gid] = sb;
    }
}

// ---------------- generic bf16 GEMM: C[M,N] = A[M,K] @ W[N,K]^T (+bias)(+act) ----------------
// REMAP: A rows are t-major (m = t*4+b); write C row at b*2048+t instead.
// CONTRACT: fused w1/contract epilogue — n = d*16+r; per (m,d): t = sum_r (acc+b2)*s[m][r]
//           via 16-lane shfl reduce, then out0[m*512+d] = resid + gated*t. No C write.
template <int BIAS, int ACT, int OUTBF, int REMAP, int CONTRACT>
__global__ __launch_bounds__(256) void k_gemm(const ushort_t* __restrict__ A, const ushort_t* __restrict__ W,
                                              const float* __restrict__ bias, float* __restrict__ Cf,
                                              ushort_t* __restrict__ Cbf, int M, int N, int K,
                                              const float* __restrict__ s, const float* __restrict__ gated,
                                              const float* __restrict__ resid, float* __restrict__ out0) {
    __shared__ __align__(16) ushort_t As[128 * 72];
    __shared__ __align__(16) ushort_t Bs[128 * 72];
    const int tid = threadIdx.x;
    const int lane = tid & 63, wave = tid >> 6;
    const int col = lane & 15, g4 = lane >> 4;
    const int wm = wave >> 1, wn = wave & 1;
    const int m0 = blockIdx.y * 128, n0 = blockIdx.x * 128;

    f32x4 acc[4][4];
#pragma unroll
    for (int i = 0; i < 4; ++i)
#pragma unroll
        for (int j = 0; j < 4; ++j) acc[i][j] = (f32x4){0.f, 0.f, 0.f, 0.f};

    for (int k0 = 0; k0 < K; k0 += 64) {
#pragma unroll
        for (int c = 0; c < 4; ++c) {
            int cid = tid + 256 * c;
            int row = cid >> 3, c8 = cid & 7;
            u32x4 va = *(const u32x4*)(A + (size_t)(m0 + row) * K + k0 + c8 * 8);
            *(u32x4*)(&As[row * 72 + c8 * 8]) = va;
            u32x4 vb = (u32x4){0u, 0u, 0u, 0u};
            if (n0 + row < N) vb = *(const u32x4*)(W + (size_t)(n0 + row) * K + k0 + c8 * 8);
            *(u32x4*)(&Bs[row * 72 + c8 * 8]) = vb;
        }
        __syncthreads();
#pragma unroll
        for (int ks = 0; ks < 2; ++ks) {
            short8 af[4], bf_[4];
#pragma unroll
            for (int i = 0; i < 4; ++i)
                af[i] = *(const short8*)(&As[(wm * 64 + i * 16 + col) * 72 + ks * 32 + g4 * 8]);
#pragma unroll
            for (int j = 0; j < 4; ++j)
                bf_[j] = *(const short8*)(&Bs[(wn * 64 + j * 16 + col) * 72 + ks * 32 + g4 * 8]);
#pragma unroll
            for (int i = 0; i < 4; ++i)
#pragma unroll
                for (int j = 0; j < 4; ++j)
                    acc[i][j] = __builtin_amdgcn_mfma_f32_16x16x32_bf16(af[i], bf_[j], acc[i][j], 0, 0, 0);
        }
        __syncthreads();
    }
    if (CONTRACT) {
#pragma unroll
        for (int j = 0; j < 4; ++j) {
            int nb = n0 + wn * 64 + j * 16;   // aligned to 16: d fixed, r = col
            int d = nb >> 4;
            float bv = bias[nb + col];
#pragma unroll
            for (int i = 0; i < 4; ++i) {
#pragma unroll
                for (int r = 0; r < 4; ++r) {
                    int m = m0 + wm * 64 + i * 16 + g4 * 4 + r;
                    float v = (acc[i][j][r] + bv) * s[(size_t)m * 16 + col];
                    v += __shfl_xor(v, 1, 16);
                    v += __shfl_xor(v, 2, 16);
                    v += __shfl_xor(v, 4, 16);
                    v += __shfl_xor(v, 8, 16);
                    if (col == 0) {
                        size_t o = (size_t)m * 512 + d;
                        out0[o] = resid[o] + gated[o] * v;
                    }
                }
            }
        }
        return;
    }
#pragma unroll
    for (int j = 0; j < 4; ++j) {
        int n = n0 + wn * 64 + j * 16 + col;
        if (n >= N) continue;
        float bv = 0.f;
        if (BIAS) bv = bias[n];
#pragma unroll
        for (int i = 0; i < 4; ++i) {
#pragma unroll
            for (int r = 0; r < 4; ++r) {
                int m = m0 + wm * 64 + i * 16 + g4 * 4 + r;
                size_t mr = REMAP ? ((size_t)(m & 3) * 2048 + (m >> 2)) : (size_t)m;
                float v = acc[i][j][r] + bv;
                if (ACT == 1) v = sigm(v);
                else if (ACT == 2) v = v * sigm(v);
                if (OUTBF) Cbf[mr * N + n] = f2bf(v);
                else Cf[mr * N + n] = v;
            }
        }
    }
}

// ---------------- persistent dual-GRU: r7-proven 1-granule poll + LDS distribution --------
// 8 blocks x 512 threads. blocks 0..3: GRU ap, 4..7: GRU su. 8 units(waves)/block,
// unit u = wg*8 + wave owns 16 h-cols, 48 W_hh rows in VGPRs.
// hseq (t-major, sentinel-prefilled) doubles as exchange + downstream GEMM input.
// Writers publish h via relaxed agent 8B atomics (data-as-flag); 384 poll lanes each
// fetch ONE foreign 8B granule into a double-buffered LDS h-tile; own units
// self-publish to LDS. ONE barrier/step; xp prefetch issued before the poll.
__global__ __launch_bounds__(512, 1) void k_gru(const float* __restrict__ Whh0, const float* __restrict__ Whh1,
                                                const float* __restrict__ bhh0, const float* __restrict__ bhh1,
                                                const ushort_t* __restrict__ xpb0, const ushort_t* __restrict__ xpb1,
                                                ushort_t* __restrict__ hseq0, ushort_t* __restrict__ hseq1) {
    __shared__ __align__(16) ushort_t HB[2][4 * 520];  // [parity][batch*520 + col], 8.3KB
    const int gru = blockIdx.x >> 2;
    const int wg = blockIdx.x & 3;
    const float* Whh = gru ? Whh1 : Whh0;
    const float* bhh = gru ? bhh1 : bhh0;
    const ushort_t* xpb = gru ? xpb1 : xpb0;
    ushort_t* hseq = gru ? hseq1 : hseq0;

    const int tid = threadIdx.x;
    const int wave = tid >> 6, lane = tid & 63;
    const int col = lane & 15, g4 = lane >> 4;
    const int u = wg * 8 + wave;  // 0..31
    const int c0 = u * 16;

    // poll assignment: 24 foreign units x 16 granules = 384; one granule per lane
    const bool gvalid = (tid < 384);
    const int uo = tid >> 4;
    const int gu = (uo < wg * 8) ? uo : uo + 8;   // skip own block's units
    const int gb = (tid >> 2) & 3, gq = tid & 3;
    const int g_u64 = gu * 4 + gq;                 // u64 index within a 512-col row
    const int g_lds = gb * 520 + gu * 16 + gq * 4; // col index in HB

    // preload bf16 A-fragments of the 48 W_hh rows this unit owns (stay in regs)
    short8 af[3][16];
#pragma unroll
    for (int m = 0; m < 3; ++m) {
        int grow = m * 512 + c0 + col;
        const float* wr = Whh + (size_t)grow * 512;
#pragma unroll
        for (int q = 0; q < 16; ++q) {
            int k = q * 32 + g4 * 8;
            f32x4 f0 = *(const f32x4*)(wr + k);
            f32x4 f1 = *(const f32x4*)(wr + k + 4);
            short8 v;
#pragma unroll
            for (int i = 0; i < 4; ++i) v[i] = (short)f2bf(f0[i]);
#pragma unroll
            for (int i = 0; i < 4; ++i) v[4 + i] = (short)f2bf(f1[i]);
            af[m][q] = v;
        }
    }

    const bool active = (col < 4);
    const int b = active ? col : 0;
    const int j0 = c0 + g4 * 4;
    f32x4 bhr = {0.f, 0.f, 0.f, 0.f}, bhz = bhr, bhn = bhr;
    if (active) {
        bhr = *(const f32x4*)(bhh + j0);
        bhz = *(const f32x4*)(bhh + 512 + j0);
        bhn = *(const f32x4*)(bhh + 1024 + j0);
    }
    float hold[4] = {0.f, 0.f, 0.f, 0.f};
    long long budget = 1LL << 21;  // bounded retries: deterministic termination safeguard

    // prologue: xp(0)
    u64_t xr8 = 0, xz8 = 0, xn8 = 0;
    if (active) {
        const ushort_t* xpt = xpb + ((size_t)b * NN) * 1536;
        xr8 = *(const u64_t*)(xpt + j0);
        xz8 = *(const u64_t*)(xpt + 512 + j0);
        xn8 = *(const u64_t*)(xpt + 1024 + j0);
    }

    for (int t = 0; t < NN; ++t) {
        // issue xp(t+1) prefetch first: HBM latency hides under poll/compute
        u64_t xrn = 0, xzn = 0, xnn = 0;
        if (active && t + 1 < NN) {
            const ushort_t* xpt = xpb + ((size_t)b * NN + t + 1) * 1536;
            xrn = *(const u64_t*)(xpt + j0);
            xzn = *(const u64_t*)(xpt + 512 + j0);
            xnn = *(const u64_t*)(xpt + 1024 + j0);
        }
        if (t > 0) {
            // poll my single foreign granule of h(t-1), deposit into LDS
            if (gvalid) {
                const u64_t* gp = (const u64_t*)hseq + ((size_t)(t - 1) * 4 + gb) * 128 + g_u64;
                u64_t v = __hip_atomic_load(gp, __ATOMIC_RELAXED, __HIP_MEMORY_SCOPE_AGENT);
                while ((v & 0xFFFFull) == SENT && --budget >= 0)
                    v = __hip_atomic_load(gp, __ATOMIC_RELAXED, __HIP_MEMORY_SCOPE_AGENT);
                *(u64_t*)(&HB[(t - 1) & 1][g_lds]) = v;
            }
        }
        __syncthreads();  // LDS h(t-1) tile complete (own units wrote at t-1 tail)
        f32x4 a0 = {0.f, 0.f, 0.f, 0.f}, a1 = a0, a2 = a0;
        if (t > 0) {
            const ushort_t* hb = &HB[(t - 1) & 1][(col & 3) * 520];
            short8 bf_[16];
#pragma unroll
            for (int q = 0; q < 16; ++q) bf_[q] = *(const short8*)(hb + q * 32 + g4 * 8);
#pragma unroll
            for (int q = 0; q < 16; ++q) {
                a0 = __builtin_amdgcn_mfma_f32_16x16x32_bf16(af[0][q], bf_[q], a0, 0, 0, 0);
                a1 = __builtin_amdgcn_mfma_f32_16x16x32_bf16(af[1][q], bf_[q], a1, 0, 0, 0);
                a2 = __builtin_amdgcn_mfma_f32_16x16x32_bf16(af[2][q], bf_[q], a2, 0, 0, 0);
            }
        }
        if (active) {
            f32x4 xr = bf4_to_f32(xr8), xz = bf4_to_f32(xz8), xn = bf4_to_f32(xn8);
            u16x4 pk;
#pragma unroll
            for (int r = 0; r < 4; ++r) {
                float rr = sigm(xr[r] + bhr[r] + a0[r]);
                float zz = sigm(xz[r] + bhz[r] + a1[r]);
                float nnv = tanhx(xn[r] + rr * (a2[r] + bhn[r]));
                float hv = (1.f - zz) * nnv + zz * hold[r];
                hold[r] = hv;
                pk[r] = f2bf(hv);
            }
            union { u16x4 p; u64_t u; } pc;
            pc.p = pk;
            // publish to other blocks (fire-and-forget, data-as-flag)
            __hip_atomic_store((u64_t*)(hseq + ((size_t)t * 4 + b) * 512 + j0), pc.u, __ATOMIC_RELAXED,
                               __HIP_MEMORY_SCOPE_AGENT);
            // self-publish to own block's LDS tile for step t+1
            *(u64_t*)(&HB[t & 1][b * 520 + j0]) = pc.u;
        }
        xr8 = xrn; xz8 = xzn; xn8 = xnn;
    }
}

// ---------------- sampled_action ----------------
__global__ __launch_bounds__(256) void k_sample(const float* __restrict__ ad, const float* __restrict__ eps,
                                                float* __restrict__ out2, int n) {
    int i = blockIdx.x * 256 + threadIdx.x;
    if (i < n) {
        float mean = ad[2 * (size_t)i];
        float lv = ad[2 * (size_t)i + 1];
        out2[i] = mean + __expf(0.5f * lv) * eps[i];
    }
}

// ---------------- assoc scan (3 phase), channels (b,d), length N ----------------
// beta_tm is t-major [(t*4+b)*512+d]; intent/gated are b-major [(b*NN+t)*512+d].
#define NC 32
#define LCH 64
__global__ __launch_bounds__(512) void k_scan1(const float* __restrict__ beta_tm, const float* __restrict__ intent,
                                               float* __restrict__ Asum, float* __restrict__ Bsum) {
    int d = threadIdx.x;
    int b = blockIdx.x / NC, c = blockIdx.x % NC;
    float A = 1.f, Bc = 0.f;
    for (int i = 0; i < LCH; ++i) {
        size_t t = (size_t)c * LCH + i;
        float a = beta_tm[(t * 4 + b) * 512 + d];
        float x = intent[((size_t)b * NN + t) * 512 + d] * (1.f - a);
        A *= a;
        Bc = a * Bc + x;
    }
    Asum[(b * NC + c) * 512 + d] = A;
    Bsum[(b * NC + c) * 512 + d] = Bc;
}
__global__ __launch_bounds__(512) void k_scan2(const float* __restrict__ Asum, const float* __restrict__ Bsum,
                                               float* __restrict__ P) {
    int d = threadIdx.x;
    int b = blockIdx.x;
    float carry = 0.f;
    for (int c = 0; c < NC; ++c) {
        int o = (b * NC + c) * 512 + d;
        P[o] = carry;
        carry = Asum[o] * carry + Bsum[o];
    }
}
__global__ __launch_bounds__(512) void k_scan3(const float* __restrict__ beta_tm, const float* __restrict__ intent,
                                               const float* __restrict__ P, float* __restrict__ gated,
                                               ushort_t* __restrict__ gated_bf) {
    int d = threadIdx.x;
    int b = blockIdx.x / NC, c = blockIdx.x % NC;
    float h = P[(b * NC + c) * 512 + d];
    for (int i = 0; i < LCH; ++i) {
        size_t t = (size_t)c * LCH + i;
        size_t idx = ((size_t)b * NN + t) * 512 + d;
        float a = beta_tm[(t * 4 + b) * 512 + d];
        float x = intent[idx] * (1.f - a);
        h = a * h + x;
        gated[idx] = h;
        gated_bf[idx] = f2bf(h);
    }
}

extern "C" void kernel_launch(void* const* d_in, const int* in_sizes, int n_in, void* d_out, int out_size, void* d_ws,
                              size_t ws_size, hipStream_t stream) {
    const float* x = (const float*)d_in[0];
    const float* eps = (const float*)d_in[1];
    const float* ap_W_ih = (const float*)d_in[2];
    const float* ap_W_hh = (const float*)d_in[3];
    const float* ap_b_ih = (const float*)d_in[4];
    const float* ap_b_hh = (const float*)d_in[5];
    const float* su_W_ih = (const float*)d_in[6];
    const float* su_W_hh = (const float*)d_in[7];
    const float* su_b_ih = (const float*)d_in[8];
    const float* su_b_hh = (const float*)d_in[9];
    const float* readout_W = (const float*)d_in[10];
    const float* readout_b = (const float*)d_in[11];
    const float* beta_W = (const float*)d_in[12];
    const float* dec_W1 = (const float*)d_in[13];
    const float* dec_b1 = (const float*)d_in[14];
    const float* dec_W2 = (const float*)d_in[15];
    const float* dec_b2 = (const float*)d_in[16];

    float* out = (float*)d_out;
    float* out_ad = out + (size_t)4194304;   // action_dist (B,N,D,2)
    float* out_sa = out + (size_t)12582912;  // sampled_action

    char* ws = (char*)d_ws;
    size_t off = 0;
    auto alloc = [&](size_t bytes) -> void* {
        off = (off + 255) & ~(size_t)255;
        void* p = ws + off;
        off += bytes;
        return p;
    };
    ushort_t* x_bf = (ushort_t*)alloc((size_t)8192 * 512 * 2);
    ushort_t* wih_ap = (ushort_t*)alloc((size_t)1536 * 512 * 2);
    ushort_t* wih_su = (ushort_t*)alloc((size_t)1536 * 512 * 2);
    ushort_t* wro = (ushort_t*)alloc((size_t)1024 * 512 * 2);
    ushort_t* wbeta = (ushort_t*)alloc((size_t)512 * 512 * 2);
    ushort_t* wd1 = (ushort_t*)alloc((size_t)1024 * 512 * 2);
    ushort_t* wd2 = (ushort_t*)alloc((size_t)8192 * 1024 * 2);
    ushort_t* w2s = (ushort_t*)alloc((size_t)16 * 1024 * 2);
    float* b2s = (float*)alloc(64);
    ushort_t* hseq_ap = (ushort_t*)alloc((size_t)8192 * 512 * 2);  // t-major exchange + GEMM input
    ushort_t* hseq_su = (ushort_t*)alloc((size_t)8192 * 512 * 2);
    float* s_buf = (float*)alloc((size_t)8192 * 16 * 4);
    char* regionA = (char*)alloc(50331648);
    char* regionB = (char*)alloc(50331648);

    ushort_t* xpb_ap = (ushort_t*)regionA;   // bf16 xp, 25.2MB
    ushort_t* xpb_su = (ushort_t*)regionB;
    // region A reuse after GRU:
    float* beta_tm = (float*)regionA;
    float* gated = (float*)(regionA + 16777216);
    ushort_t* gated_bf = (ushort_t*)(regionA + 2 * 16777216);
    float* Asum = (float*)(regionA + 41943040);
    float* Bsum = (float*)(regionA + 41943040 + 262144);
    float* Pbuf = (float*)(regionA + 41943040 + 524288);
    // region B reuse after GRU:
    ushort_t* hdec_bf = (ushort_t*)regionB;

    // zero KL output
    hipMemsetAsync(out + (size_t)(out_size - 1), 0, 4, stream);

    // sentinel-fill the h exchange buffers (re-done every launch; replay-safe)
    k_fill<<<2048, 256, 0, stream>>>((u32x4*)hseq_ap, 524288);
    k_fill<<<2048, 256, 0, stream>>>((u32x4*)hseq_su, 524288);

    // weight / input conversions to bf16
    k_cvt<<<768, 256, 0, stream>>>(ap_W_ih, wih_ap, 196608);
    k_cvt<<<768, 256, 0, stream>>>(su_W_ih, wih_su, 196608);
    k_cvt<<<512, 256, 0, stream>>>(readout_W, wro, 131072);
    k_cvt<<<256, 256, 0, stream>>>(beta_W, wbeta, 65536);
    k_cvt<<<512, 256, 0, stream>>>(dec_W1, wd1, 131072);
    k_cvt<<<8192, 256, 0, stream>>>(dec_W2, wd2, 2097152);
    k_cvt<<<4096, 256, 0, stream>>>(x, x_bf, 1048576);
    k_w2s<<<64, 256, 0, stream>>>(dec_W2, dec_b2, w2s, b2s);

    // xp projections (bf16 out)
    k_gemm<1, 0, 1, 0, 0><<<dim3(12, 64), 256, 0, stream>>>(x_bf, wih_ap, ap_b_ih, nullptr, xpb_ap, 8192, 1536, 512,
                                                            nullptr, nullptr, nullptr, nullptr);
    k_gemm<1, 0, 1, 0, 0><<<dim3(12, 64), 256, 0, stream>>>(x_bf, wih_su, su_b_ih, nullptr, xpb_su, 8192, 1536, 512,
                                                            nullptr, nullptr, nullptr, nullptr);

    // both GRUs: 8 persistent blocks (4 per GRU), 1-granule poll + LDS distribution
    k_gru<<<8, 512, 0, stream>>>(ap_W_hh, su_W_hh, ap_b_hh, su_b_hh, xpb_ap, xpb_su, hseq_ap, hseq_su);

    // readout -> action_dist (REMAP t-major rows -> b-major out), then sampled_action
    k_gemm<1, 0, 0, 1, 0><<<dim3(8, 64), 256, 0, stream>>>(hseq_ap, wro, readout_b, out_ad, nullptr, 8192, 1024, 512,
                                                           nullptr, nullptr, nullptr, nullptr);
    k_sample<<<16384, 256, 0, stream>>>(out_ad, eps, out_sa, 4194304);

    // switch_beta (t-major output; scan consumes t-major)
    k_gemm<0, 1, 0, 0, 0><<<dim3(4, 64), 256, 0, stream>>>(hseq_su, wbeta, nullptr, beta_tm, nullptr, 8192, 512, 512,
                                                           nullptr, nullptr, nullptr, nullptr);

    // associative scan -> gated
    k_scan1<<<4 * NC, 512, 0, stream>>>(beta_tm, out_sa, Asum, Bsum);
    k_scan2<<<4, 512, 0, stream>>>(Asum, Bsum, Pbuf);
    k_scan3<<<4 * NC, 512, 0, stream>>>(beta_tm, out_sa, Pbuf, gated, gated_bf);

    // decoder layer 1 (SiLU, bf16 out)
    k_gemm<1, 2, 1, 0, 0><<<dim3(8, 64), 256, 0, stream>>>(gated_bf, wd1, dec_b1, nullptr, hdec_bf, 8192, 1024, 512,
                                                           nullptr, nullptr, nullptr, nullptr);

    // s = hdec @ W2s^T + b2s
    k_gemm<1, 0, 0, 0, 0><<<dim3(1, 64), 256, 0, stream>>>(hdec_bf, w2s, b2s, s_buf, nullptr, 8192, 16, 1024,
                                                           nullptr, nullptr, nullptr, nullptr);

    // fused w1 GEMM + r-contraction + final output (single launch, no w1s buffer)
    k_gemm<1, 0, 0, 0, 1><<<dim3(64, 64), 256, 0, stream>>>(hdec_bf, wd2, dec_b2, nullptr, nullptr, 8192, 8192, 1024,
                                                            s_buf, gated, x, out);
}

// Round 14
// 6313.434 us; speedup vs baseline: 1.1625x; 1.0161x over previous
//
#include <hip/hip_runtime.h>
#include <hip/hip_bf16.h>

typedef unsigned short ushort_t;
typedef unsigned long long u64_t;
typedef __attribute__((ext_vector_type(4))) float f32x4;
typedef __attribute__((ext_vector_type(8))) short short8;
typedef __attribute__((ext_vector_type(4))) unsigned int u32x4;
typedef __attribute__((ext_vector_type(4))) ushort_t u16x4;

#define BB 4
#define NN 2048
#define DD 512
#define H3 1536
#define SENT 0x7FC0ull  // bf16 qNaN: impossible h value since |h| < 1 strictly

__device__ __forceinline__ ushort_t f2bf(float f) {
    union { float f; unsigned u; } v; v.f = f;
    unsigned r = v.u + 0x7FFFu + ((v.u >> 16) & 1u);
    return (ushort_t)(r >> 16);
}
__device__ __forceinline__ float sigm(float x) { return 1.f / (1.f + __expf(-x)); }
__device__ __forceinline__ float tanhx(float x) { return 1.f - 2.f / (__expf(2.f * x) + 1.f); }
__device__ __forceinline__ f32x4 bf4_to_f32(u64_t v) {
    f32x4 r;
#pragma unroll
    for (int i = 0; i < 4; ++i) {
        union { unsigned u; float f; } c;
        c.u = (unsigned)((v >> (16 * i)) & 0xFFFFull) << 16;
        r[i] = c.f;
    }
    return r;
}

// ---------------- generic cvt fp32 -> bf16 ----------------
__global__ __launch_bounds__(256) void k_cvt(const float* __restrict__ src, ushort_t* __restrict__ dst, int n4) {
    int i = blockIdx.x * 256 + threadIdx.x;
    if (i < n4) {
        f32x4 f = *(const f32x4*)(src + 4 * (size_t)i);
        u16x4 u;
#pragma unroll
        for (int r = 0; r < 4; ++r) u[r] = f2bf(f[r]);
        *(u16x4*)(dst + 4 * (size_t)i) = u;
    }
}

// ---------------- sentinel fill (16B per thread) ----------------
__global__ __launch_bounds__(256) void k_fill(u32x4* __restrict__ dst, int n16) {
    int i = blockIdx.x * 256 + threadIdx.x;
    if (i < n16) dst[i] = (u32x4){0x7FC07FC0u, 0x7FC07FC0u, 0x7FC07FC0u, 0x7FC07FC0u};
}

// ---------------- W2s reduction: rows 8192..16383 of dec_W2 summed over d ----------------
__global__ __launch_bounds__(256) void k_w2s(const float* __restrict__ W2, const float* __restrict__ b2,
                                             ushort_t* __restrict__ W2s, float* __restrict__ b2s) {
    int gid = blockIdx.x * 256 + threadIdx.x; // 0..16383
    int r = gid >> 10, k = gid & 1023;
    float s = 0.f;
    for (int d = 0; d < 512; ++d) s += W2[(size_t)(8192 + d * 16 + r) * 1024 + k];
    W2s[r * 1024 + k] = f2bf(s);
    if (gid < 16) {
        float sb = 0.f;
        for (int d = 0; d < 512; ++d) sb += b2[8192 + d * 16 + gid];
        b2s[gid] = sb;
    }
}

// ---------------- generic bf16 GEMM: C[M,N] = A[M,K] @ W[N,K]^T (+bias)(+act) ----------------
// REMAP: A rows are t-major (m = t*4+b); write C row at b*2048+t instead.
// CONTRACT: fused w1/contract epilogue — n = d*16+r; per (m,d): t = sum_r (acc+b2)*s[m][r]
//           via 16-lane shfl reduce, then out0[m*512+d] = resid + gated*t. No C write.
template <int BIAS, int ACT, int OUTBF, int REMAP, int CONTRACT>
__global__ __launch_bounds__(256) void k_gemm(const ushort_t* __restrict__ A, const ushort_t* __restrict__ W,
                                              const float* __restrict__ bias, float* __restrict__ Cf,
                                              ushort_t* __restrict__ Cbf, int M, int N, int K,
                                              const float* __restrict__ s, const float* __restrict__ gated,
                                              const float* __restrict__ resid, float* __restrict__ out0) {
    __shared__ __align__(16) ushort_t As[128 * 72];
    __shared__ __align__(16) ushort_t Bs[128 * 72];
    const int tid = threadIdx.x;
    const int lane = tid & 63, wave = tid >> 6;
    const int col = lane & 15, g4 = lane >> 4;
    const int wm = wave >> 1, wn = wave & 1;
    const int m0 = blockIdx.y * 128, n0 = blockIdx.x * 128;

    f32x4 acc[4][4];
#pragma unroll
    for (int i = 0; i < 4; ++i)
#pragma unroll
        for (int j = 0; j < 4; ++j) acc[i][j] = (f32x4){0.f, 0.f, 0.f, 0.f};

    for (int k0 = 0; k0 < K; k0 += 64) {
#pragma unroll
        for (int c = 0; c < 4; ++c) {
            int cid = tid + 256 * c;
            int row = cid >> 3, c8 = cid & 7;
            u32x4 va = *(const u32x4*)(A + (size_t)(m0 + row) * K + k0 + c8 * 8);
            *(u32x4*)(&As[row * 72 + c8 * 8]) = va;
            u32x4 vb = (u32x4){0u, 0u, 0u, 0u};
            if (n0 + row < N) vb = *(const u32x4*)(W + (size_t)(n0 + row) * K + k0 + c8 * 8);
            *(u32x4*)(&Bs[row * 72 + c8 * 8]) = vb;
        }
        __syncthreads();
#pragma unroll
        for (int ks = 0; ks < 2; ++ks) {
            short8 af[4], bf_[4];
#pragma unroll
            for (int i = 0; i < 4; ++i)
                af[i] = *(const short8*)(&As[(wm * 64 + i * 16 + col) * 72 + ks * 32 + g4 * 8]);
#pragma unroll
            for (int j = 0; j < 4; ++j)
                bf_[j] = *(const short8*)(&Bs[(wn * 64 + j * 16 + col) * 72 + ks * 32 + g4 * 8]);
#pragma unroll
            for (int i = 0; i < 4; ++i)
#pragma unroll
                for (int j = 0; j < 4; ++j)
                    acc[i][j] = __builtin_amdgcn_mfma_f32_16x16x32_bf16(af[i], bf_[j], acc[i][j], 0, 0, 0);
        }
        __syncthreads();
    }
    if (CONTRACT) {
#pragma unroll
        for (int j = 0; j < 4; ++j) {
            int nb = n0 + wn * 64 + j * 16;   // aligned to 16: d fixed, r = col
            int d = nb >> 4;
            float bv = bias[nb + col];
#pragma unroll
            for (int i = 0; i < 4; ++i) {
#pragma unroll
                for (int r = 0; r < 4; ++r) {
                    int m = m0 + wm * 64 + i * 16 + g4 * 4 + r;
                    float v = (acc[i][j][r] + bv) * s[(size_t)m * 16 + col];
                    v += __shfl_xor(v, 1, 16);
                    v += __shfl_xor(v, 2, 16);
                    v += __shfl_xor(v, 4, 16);
                    v += __shfl_xor(v, 8, 16);
                    if (col == 0) {
                        size_t o = (size_t)m * 512 + d;
                        out0[o] = resid[o] + gated[o] * v;
                    }
                }
            }
        }
        return;
    }
#pragma unroll
    for (int j = 0; j < 4; ++j) {
        int n = n0 + wn * 64 + j * 16 + col;
        if (n >= N) continue;
        float bv = 0.f;
        if (BIAS) bv = bias[n];
#pragma unroll
        for (int i = 0; i < 4; ++i) {
#pragma unroll
            for (int r = 0; r < 4; ++r) {
                int m = m0 + wm * 64 + i * 16 + g4 * 4 + r;
                size_t mr = REMAP ? ((size_t)(m & 3) * 2048 + (m >> 2)) : (size_t)m;
                float v = acc[i][j][r] + bv;
                if (ACT == 1) v = sigm(v);
                else if (ACT == 2) v = v * sigm(v);
                if (OUTBF) Cbf[mr * N + n] = f2bf(v);
                else Cf[mr * N + n] = v;
            }
        }
    }
}

// ---------------- persistent dual-GRU: pipelined-poll (depth 4) + LDS distribution --------
// 8 blocks x 512 threads. blocks 0..3: GRU ap, 4..7: GRU su. 8 units(waves)/block,
// unit u = wg*8 + wave owns 16 h-cols, 48 W_hh rows in VGPRs.
// hseq (t-major, sentinel-prefilled) doubles as exchange + downstream GEMM input.
// Writers publish h via relaxed agent 8B atomics (data-as-flag); 384 poll lanes each
// poll ONE foreign 8B granule with a 4-deep in-flight load pipeline (detection
// quantum ~RT/4 instead of RT), deposit into double-buffered LDS; own units
// self-publish to LDS. ONE barrier/step; xp prefetch issued before the poll.
__global__ __launch_bounds__(512, 1) void k_gru(const float* __restrict__ Whh0, const float* __restrict__ Whh1,
                                                const float* __restrict__ bhh0, const float* __restrict__ bhh1,
                                                const ushort_t* __restrict__ xpb0, const ushort_t* __restrict__ xpb1,
                                                ushort_t* __restrict__ hseq0, ushort_t* __restrict__ hseq1) {
    __shared__ __align__(16) ushort_t HB[2][4 * 520];  // [parity][batch*520 + col], 8.3KB
    const int gru = blockIdx.x >> 2;
    const int wg = blockIdx.x & 3;
    const float* Whh = gru ? Whh1 : Whh0;
    const float* bhh = gru ? bhh1 : bhh0;
    const ushort_t* xpb = gru ? xpb1 : xpb0;
    ushort_t* hseq = gru ? hseq1 : hseq0;

    const int tid = threadIdx.x;
    const int wave = tid >> 6, lane = tid & 63;
    const int col = lane & 15, g4 = lane >> 4;
    const int u = wg * 8 + wave;  // 0..31
    const int c0 = u * 16;

    // poll assignment: 24 foreign units x 16 granules = 384; one granule per lane
    const bool gvalid = (tid < 384);
    const int uo = tid >> 4;
    const int gu = (uo < wg * 8) ? uo : uo + 8;   // skip own block's units
    const int gb = (tid >> 2) & 3, gq = tid & 3;
    const int g_u64 = gu * 4 + gq;                 // u64 index within a 512-col row
    const int g_lds = gb * 520 + gu * 16 + gq * 4; // col index in HB

    // preload bf16 A-fragments of the 48 W_hh rows this unit owns (stay in regs)
    short8 af[3][16];
#pragma unroll
    for (int m = 0; m < 3; ++m) {
        int grow = m * 512 + c0 + col;
        const float* wr = Whh + (size_t)grow * 512;
#pragma unroll
        for (int q = 0; q < 16; ++q) {
            int k = q * 32 + g4 * 8;
            f32x4 f0 = *(const f32x4*)(wr + k);
            f32x4 f1 = *(const f32x4*)(wr + k + 4);
            short8 v;
#pragma unroll
            for (int i = 0; i < 4; ++i) v[i] = (short)f2bf(f0[i]);
#pragma unroll
            for (int i = 0; i < 4; ++i) v[4 + i] = (short)f2bf(f1[i]);
            af[m][q] = v;
        }
    }

    const bool active = (col < 4);
    const int b = active ? col : 0;
    const int j0 = c0 + g4 * 4;
    f32x4 bhr = {0.f, 0.f, 0.f, 0.f}, bhz = bhr, bhn = bhr;
    if (active) {
        bhr = *(const f32x4*)(bhh + j0);
        bhz = *(const f32x4*)(bhh + 512 + j0);
        bhn = *(const f32x4*)(bhh + 1024 + j0);
    }
    float hold[4] = {0.f, 0.f, 0.f, 0.f};
    long long budget = 1LL << 21;  // bounded retries: deterministic termination safeguard

    // prologue: xp(0)
    u64_t xr8 = 0, xz8 = 0, xn8 = 0;
    if (active) {
        const ushort_t* xpt = xpb + ((size_t)b * NN) * 1536;
        xr8 = *(const u64_t*)(xpt + j0);
        xz8 = *(const u64_t*)(xpt + 512 + j0);
        xn8 = *(const u64_t*)(xpt + 1024 + j0);
    }

    for (int t = 0; t < NN; ++t) {
        // issue xp(t+1) prefetch first: HBM latency hides under poll/compute
        u64_t xrn = 0, xzn = 0, xnn = 0;
        if (active && t + 1 < NN) {
            const ushort_t* xpt = xpb + ((size_t)b * NN + t + 1) * 1536;
            xrn = *(const u64_t*)(xpt + j0);
            xzn = *(const u64_t*)(xpt + 512 + j0);
            xnn = *(const u64_t*)(xpt + 1024 + j0);
        }
        if (t > 0) {
            // pipelined poll: 4 same-address loads in flight; check oldest, refill newest.
            // Detection quantum ~RT/4 vs serial retry's full RT.
            if (gvalid) {
                const u64_t* gp = (const u64_t*)hseq + ((size_t)(t - 1) * 4 + gb) * 128 + g_u64;
                u64_t v0 = __hip_atomic_load(gp, __ATOMIC_RELAXED, __HIP_MEMORY_SCOPE_AGENT);
                u64_t v1 = __hip_atomic_load(gp, __ATOMIC_RELAXED, __HIP_MEMORY_SCOPE_AGENT);
                u64_t v2 = __hip_atomic_load(gp, __ATOMIC_RELAXED, __HIP_MEMORY_SCOPE_AGENT);
                u64_t v3 = __hip_atomic_load(gp, __ATOMIC_RELAXED, __HIP_MEMORY_SCOPE_AGENT);
                while ((v0 & 0xFFFFull) == SENT && --budget >= 0) {
                    v0 = v1; v1 = v2; v2 = v3;
                    v3 = __hip_atomic_load(gp, __ATOMIC_RELAXED, __HIP_MEMORY_SCOPE_AGENT);
                }
                *(u64_t*)(&HB[(t - 1) & 1][g_lds]) = v0;
            }
        }
        __syncthreads();  // LDS h(t-1) tile complete (own units wrote at t-1 tail)
        f32x4 a0 = {0.f, 0.f, 0.f, 0.f}, a1 = a0, a2 = a0;
        if (t > 0) {
            const ushort_t* hb = &HB[(t - 1) & 1][(col & 3) * 520];
            short8 bf_[16];
#pragma unroll
            for (int q = 0; q < 16; ++q) bf_[q] = *(const short8*)(hb + q * 32 + g4 * 8);
#pragma unroll
            for (int q = 0; q < 16; ++q) {
                a0 = __builtin_amdgcn_mfma_f32_16x16x32_bf16(af[0][q], bf_[q], a0, 0, 0, 0);
                a1 = __builtin_amdgcn_mfma_f32_16x16x32_bf16(af[1][q], bf_[q], a1, 0, 0, 0);
                a2 = __builtin_amdgcn_mfma_f32_16x16x32_bf16(af[2][q], bf_[q], a2, 0, 0, 0);
            }
        }
        if (active) {
            f32x4 xr = bf4_to_f32(xr8), xz = bf4_to_f32(xz8), xn = bf4_to_f32(xn8);
            u16x4 pk;
#pragma unroll
            for (int r = 0; r < 4; ++r) {
                float rr = sigm(xr[r] + bhr[r] + a0[r]);
                float zz = sigm(xz[r] + bhz[r] + a1[r]);
                float nnv = tanhx(xn[r] + rr * (a2[r] + bhn[r]));
                float hv = (1.f - zz) * nnv + zz * hold[r];
                hold[r] = hv;
                pk[r] = f2bf(hv);
            }
            union { u16x4 p; u64_t u; } pc;
            pc.p = pk;
            // publish to other blocks (fire-and-forget, data-as-flag)
            __hip_atomic_store((u64_t*)(hseq + ((size_t)t * 4 + b) * 512 + j0), pc.u, __ATOMIC_RELAXED,
                               __HIP_MEMORY_SCOPE_AGENT);
            // self-publish to own block's LDS tile for step t+1
            *(u64_t*)(&HB[t & 1][b * 520 + j0]) = pc.u;
        }
        xr8 = xrn; xz8 = xzn; xn8 = xnn;
    }
}

// ---------------- sampled_action ----------------
__global__ __launch_bounds__(256) void k_sample(const float* __restrict__ ad, const float* __restrict__ eps,
                                                float* __restrict__ out2, int n) {
    int i = blockIdx.x * 256 + threadIdx.x;
    if (i < n) {
        float mean = ad[2 * (size_t)i];
        float lv = ad[2 * (size_t)i + 1];
        out2[i] = mean + __expf(0.5f * lv) * eps[i];
    }
}

// ---------------- assoc scan (3 phase), channels (b,d), length N ----------------
// beta_tm is t-major [(t*4+b)*512+d]; intent/gated are b-major [(b*NN+t)*512+d].
#define NC 32
#define LCH 64
__global__ __launch_bounds__(512) void k_scan1(const float* __restrict__ beta_tm, const float* __restrict__ intent,
                                               float* __restrict__ Asum, float* __restrict__ Bsum) {
    int d = threadIdx.x;
    int b = blockIdx.x / NC, c = blockIdx.x % NC;
    float A = 1.f, Bc = 0.f;
    for (int i = 0; i < LCH; ++i) {
        size_t t = (size_t)c * LCH + i;
        float a = beta_tm[(t * 4 + b) * 512 + d];
        float x = intent[((size_t)b * NN + t) * 512 + d] * (1.f - a);
        A *= a;
        Bc = a * Bc + x;
    }
    Asum[(b * NC + c) * 512 + d] = A;
    Bsum[(b * NC + c) * 512 + d] = Bc;
}
__global__ __launch_bounds__(512) void k_scan2(const float* __restrict__ Asum, const float* __restrict__ Bsum,
                                               float* __restrict__ P) {
    int d = threadIdx.x;
    int b = blockIdx.x;
    float carry = 0.f;
    for (int c = 0; c < NC; ++c) {
        int o = (b * NC + c) * 512 + d;
        P[o] = carry;
        carry = Asum[o] * carry + Bsum[o];
    }
}
__global__ __launch_bounds__(512) void k_scan3(const float* __restrict__ beta_tm, const float* __restrict__ intent,
                                               const float* __restrict__ P, float* __restrict__ gated,
                                               ushort_t* __restrict__ gated_bf) {
    int d = threadIdx.x;
    int b = blockIdx.x / NC, c = blockIdx.x % NC;
    float h = P[(b * NC + c) * 512 + d];
    for (int i = 0; i < LCH; ++i) {
        size_t t = (size_t)c * LCH + i;
        size_t idx = ((size_t)b * NN + t) * 512 + d;
        float a = beta_tm[(t * 4 + b) * 512 + d];
        float x = intent[idx] * (1.f - a);
        h = a * h + x;
        gated[idx] = h;
        gated_bf[idx] = f2bf(h);
    }
}

extern "C" void kernel_launch(void* const* d_in, const int* in_sizes, int n_in, void* d_out, int out_size, void* d_ws,
                              size_t ws_size, hipStream_t stream) {
    const float* x = (const float*)d_in[0];
    const float* eps = (const float*)d_in[1];
    const float* ap_W_ih = (const float*)d_in[2];
    const float* ap_W_hh = (const float*)d_in[3];
    const float* ap_b_ih = (const float*)d_in[4];
    const float* ap_b_hh = (const float*)d_in[5];
    const float* su_W_ih = (const float*)d_in[6];
    const float* su_W_hh = (const float*)d_in[7];
    const float* su_b_ih = (const float*)d_in[8];
    const float* su_b_hh = (const float*)d_in[9];
    const float* readout_W = (const float*)d_in[10];
    const float* readout_b = (const float*)d_in[11];
    const float* beta_W = (const float*)d_in[12];
    const float* dec_W1 = (const float*)d_in[13];
    const float* dec_b1 = (const float*)d_in[14];
    const float* dec_W2 = (const float*)d_in[15];
    const float* dec_b2 = (const float*)d_in[16];

    float* out = (float*)d_out;
    float* out_ad = out + (size_t)4194304;   // action_dist (B,N,D,2)
    float* out_sa = out + (size_t)12582912;  // sampled_action

    char* ws = (char*)d_ws;
    size_t off = 0;
    auto alloc = [&](size_t bytes) -> void* {
        off = (off + 255) & ~(size_t)255;
        void* p = ws + off;
        off += bytes;
        return p;
    };
    ushort_t* x_bf = (ushort_t*)alloc((size_t)8192 * 512 * 2);
    ushort_t* wih_ap = (ushort_t*)alloc((size_t)1536 * 512 * 2);
    ushort_t* wih_su = (ushort_t*)alloc((size_t)1536 * 512 * 2);
    ushort_t* wro = (ushort_t*)alloc((size_t)1024 * 512 * 2);
    ushort_t* wbeta = (ushort_t*)alloc((size_t)512 * 512 * 2);
    ushort_t* wd1 = (ushort_t*)alloc((size_t)1024 * 512 * 2);
    ushort_t* wd2 = (ushort_t*)alloc((size_t)8192 * 1024 * 2);
    ushort_t* w2s = (ushort_t*)alloc((size_t)16 * 1024 * 2);
    float* b2s = (float*)alloc(64);
    ushort_t* hseq_ap = (ushort_t*)alloc((size_t)8192 * 512 * 2);  // t-major exchange + GEMM input
    ushort_t* hseq_su = (ushort_t*)alloc((size_t)8192 * 512 * 2);
    float* s_buf = (float*)alloc((size_t)8192 * 16 * 4);
    char* regionA = (char*)alloc(50331648);
    char* regionB = (char*)alloc(50331648);

    ushort_t* xpb_ap = (ushort_t*)regionA;   // bf16 xp, 25.2MB
    ushort_t* xpb_su = (ushort_t*)regionB;
    // region A reuse after GRU:
    float* beta_tm = (float*)regionA;
    float* gated = (float*)(regionA + 16777216);
    ushort_t* gated_bf = (ushort_t*)(regionA + 2 * 16777216);
    float* Asum = (float*)(regionA + 41943040);
    float* Bsum = (float*)(regionA + 41943040 + 262144);
    float* Pbuf = (float*)(regionA + 41943040 + 524288);
    // region B reuse after GRU:
    ushort_t* hdec_bf = (ushort_t*)regionB;

    // zero KL output
    hipMemsetAsync(out + (size_t)(out_size - 1), 0, 4, stream);

    // sentinel-fill the h exchange buffers (re-done every launch; replay-safe)
    k_fill<<<2048, 256, 0, stream>>>((u32x4*)hseq_ap, 524288);
    k_fill<<<2048, 256, 0, stream>>>((u32x4*)hseq_su, 524288);

    // weight / input conversions to bf16
    k_cvt<<<768, 256, 0, stream>>>(ap_W_ih, wih_ap, 196608);
    k_cvt<<<768, 256, 0, stream>>>(su_W_ih, wih_su, 196608);
    k_cvt<<<512, 256, 0, stream>>>(readout_W, wro, 131072);
    k_cvt<<<256, 256, 0, stream>>>(beta_W, wbeta, 65536);
    k_cvt<<<512, 256, 0, stream>>>(dec_W1, wd1, 131072);
    k_cvt<<<8192, 256, 0, stream>>>(dec_W2, wd2, 2097152);
    k_cvt<<<4096, 256, 0, stream>>>(x, x_bf, 1048576);
    k_w2s<<<64, 256, 0, stream>>>(dec_W2, dec_b2, w2s, b2s);

    // xp projections (bf16 out)
    k_gemm<1, 0, 1, 0, 0><<<dim3(12, 64), 256, 0, stream>>>(x_bf, wih_ap, ap_b_ih, nullptr, xpb_ap, 8192, 1536, 512,
                                                            nullptr, nullptr, nullptr, nullptr);
    k_gemm<1, 0, 1, 0, 0><<<dim3(12, 64), 256, 0, stream>>>(x_bf, wih_su, su_b_ih, nullptr, xpb_su, 8192, 1536, 512,
                                                            nullptr, nullptr, nullptr, nullptr);

    // both GRUs: 8 persistent blocks (4 per GRU), pipelined 1-granule poll + LDS distribution
    k_gru<<<8, 512, 0, stream>>>(ap_W_hh, su_W_hh, ap_b_hh, su_b_hh, xpb_ap, xpb_su, hseq_ap, hseq_su);

    // readout -> action_dist (REMAP t-major rows -> b-major out), then sampled_action
    k_gemm<1, 0, 0, 1, 0><<<dim3(8, 64), 256, 0, stream>>>(hseq_ap, wro, readout_b, out_ad, nullptr, 8192, 1024, 512,
                                                           nullptr, nullptr, nullptr, nullptr);
    k_sample<<<16384, 256, 0, stream>>>(out_ad, eps, out_sa, 4194304);

    // switch_beta (t-major output; scan consumes t-major)
    k_gemm<0, 1, 0, 0, 0><<<dim3(4, 64), 256, 0, stream>>>(hseq_su, wbeta, nullptr, beta_tm, nullptr, 8192, 512, 512,
                                                           nullptr, nullptr, nullptr, nullptr);

    // associative scan -> gated
    k_scan1<<<4 * NC, 512, 0, stream>>>(beta_tm, out_sa, Asum, Bsum);
    k_scan2<<<4, 512, 0, stream>>>(Asum, Bsum, Pbuf);
    k_scan3<<<4 * NC, 512, 0, stream>>>(beta_tm, out_sa, Pbuf, gated, gated_bf);

    // decoder layer 1 (SiLU, bf16 out)
    k_gemm<1, 2, 1, 0, 0><<<dim3(8, 64), 256, 0, stream>>>(gated_bf, wd1, dec_b1, nullptr, hdec_bf, 8192, 1024, 512,
                                                           nullptr, nullptr, nullptr, nullptr);

    // s = hdec @ W2s^T + b2s
    k_gemm<1, 0, 0, 0, 0><<<dim3(1, 64), 256, 0, stream>>>(hdec_bf, w2s, b2s, s_buf, nullptr, 8192, 16, 1024,
                                                           nullptr, nullptr, nullptr, nullptr);

    // fused w1 GEMM + r-contraction + final output (single launch, no w1s buffer)
    k_gemm<1, 0, 0, 0, 1><<<dim3(64, 64), 256, 0, stream>>>(hdec_bf, wd2, dec_b2, nullptr, nullptr, 8192, 8192, 1024,
                                                            s_buf, gated, x, out);
}